// Round 9
// baseline (132.647 us; speedup 1.0000x reference)
//
#include <hip/hip_runtime.h>
#include <math.h>

#define B_  8
#define S_  512
#define D_  512
#define H_  8
#define DK_ 64

typedef __attribute__((ext_vector_type(8))) short short8;
typedef __attribute__((ext_vector_type(4))) float f32x4;

#define MFMA_BF16(a, b, c) __builtin_amdgcn_mfma_f32_16x16x32_bf16(a, b, c, 0, 0, 0)

__device__ __forceinline__ unsigned bf16_rne(float x) {
    unsigned u = __float_as_uint(x);
    return (u + 0x7FFFu + ((u >> 16) & 1u)) >> 16;
}
__device__ __forceinline__ float bf16f(unsigned h) { return __uint_as_float(h << 16); }

// async global->LDS, 16B per lane; lds dest = uniform base + lane*16
__device__ __forceinline__ void glds16(const ushort* g, ushort* l) {
    __builtin_amdgcn_global_load_lds(
        (const __attribute__((address_space(1))) unsigned int*)g,
        (__attribute__((address_space(3))) unsigned int*)l,
        16, 0, 0);
}

// ---------------------------------------------------------------------------
// fp32 -> split-bf16 planes for x and the four weight matrices (one launch)
// ---------------------------------------------------------------------------
__global__ __launch_bounds__(256)
void conv_pl(const float* __restrict__ x,
             const float* __restrict__ wq, const float* __restrict__ wk,
             const float* __restrict__ wv, const float* __restrict__ wo,
             ushort* __restrict__ Xh, ushort* __restrict__ Xl,
             ushort* __restrict__ Wqh, ushort* __restrict__ Wql,
             ushort* __restrict__ Wkh, ushort* __restrict__ Wkl,
             ushort* __restrict__ Wvh, ushort* __restrict__ Wvl,
             ushort* __restrict__ Woh, ushort* __restrict__ Wol) {
    const int bid = blockIdx.x;
    const float* src; ushort* dh; ushort* dl; int i4;
    if (bid < 2048) {
        src = x; dh = Xh; dl = Xl; i4 = bid * 256 + threadIdx.x;
    } else {
        const int r = bid - 2048;
        const int wsel = r >> 8;
        src = (wsel == 0) ? wq : (wsel == 1) ? wk : (wsel == 2) ? wv : wo;
        dh  = (wsel == 0) ? Wqh : (wsel == 1) ? Wkh : (wsel == 2) ? Wvh : Woh;
        dl  = (wsel == 0) ? Wql : (wsel == 1) ? Wkl : (wsel == 2) ? Wvl : Wol;
        i4 = (r & 255) * 256 + threadIdx.x;
    }
    const float4 v = ((const float4*)src)[i4];
    unsigned h[4], l[4];
    const float* vp = &v.x;
    #pragma unroll
    for (int j = 0; j < 4; ++j) { h[j] = bf16_rne(vp[j]); l[j] = bf16_rne(vp[j] - bf16f(h[j])); }
    ((uint2*)dh)[i4] = make_uint2(h[0] | (h[1] << 16), h[2] | (h[3] << 16));
    ((uint2*)dl)[i4] = make_uint2(l[0] | (l[1] << 16), l[2] | (l[3] << 16));
}

// ---------------------------------------------------------------------------
// rel_embed [1023][512] fp32 -> per-head padded bf16 table Rg[8][1152][64]
// ---------------------------------------------------------------------------
__global__ __launch_bounds__(256)
void conv_rel(const float* __restrict__ rel, ushort* __restrict__ Rg) {
    const int idx = blockIdx.x * 256 + threadIdx.x;
    const int d2 = idx & 31;
    const int rr = (idx >> 5) % 1152;
    const int h  = idx / (1152 * 32);
    unsigned v0 = 0, v1 = 0;
    if (rr >= 64 && rr < 64 + 1023) {
        const float* s = &rel[(size_t)(rr - 64) * 512 + h * 64 + d2 * 2];
        v0 = bf16_rne(s[0]); v1 = bf16_rne(s[1]);
    }
    *(uint*)&Rg[((size_t)h * 1152 + rr) * 64 + d2 * 2] = v0 | (v1 << 16);
}

// ---------------------------------------------------------------------------
// Split-bf16 MFMA GEMM: D = X . Y^T (+bias)*scale, K=512, tile 64x64, 4 waves.
// XB: 0 = X row-major; 1 = X planes in (b,h,s,dk) blocked layout
// OM: 0 = fp32 row-major out; 2 = split planes (b,h,s,dk); 3 = V^T hi-plane only
// ---------------------------------------------------------------------------
template<int XB, int OM>
__global__ __launch_bounds__(256, 2)
void gemm_mfma(const ushort* __restrict__ Xhp, const ushort* __restrict__ Xlp,
               const ushort* __restrict__ Yh0, const ushort* __restrict__ Yl0,
               const ushort* __restrict__ Yh1, const ushort* __restrict__ Yl1,
               const float* __restrict__ bias0, const float* __restrict__ bias1,
               float scale0, float scale1,
               float* __restrict__ outF,
               ushort* __restrict__ oh0, ushort* __restrict__ ol0,
               ushort* __restrict__ oh1, ushort* __restrict__ ol1) {
    __shared__ ushort Xs[2][2][64 * 64];
    __shared__ ushort Ys[2][2][64 * 64];

    const int z = blockIdx.z;
    const ushort* Yhp = z ? Yh1 : Yh0;
    const ushort* Ylp = z ? Yl1 : Yl0;
    const float*  bias = z ? bias1 : bias0;
    const float   scale = z ? scale1 : scale0;
    ushort* ohp = z ? oh1 : oh0;
    ushort* olp = z ? ol1 : ol0;

    const int tid = threadIdx.x;
    const int w = tid >> 6, lane = tid & 63;
    const int g = lane >> 4, c = lane & 15;
    const int rloc = lane >> 3, cc8 = lane & 7;
    const int cp = cc8 ^ rloc;
    const int r0 = blockIdx.y * 64;
    const int c0 = blockIdx.x * 64;

    const f32x4 fz = {0.f, 0.f, 0.f, 0.f};
    f32x4 acc[2][2] = {{fz, fz}, {fz, fz}};

    auto stage = [&](int kt, int buf) {
        const int k0 = kt * 64;
        const ushort* gb; ushort* lb; size_t rstr;
        if (w < 2) {
            const ushort* Xp = (w == 1) ? Xlp : Xhp;
            if (XB == 0) { gb = Xp + (size_t)r0 * 512 + k0; rstr = 512; }
            else {
                const int b = r0 >> 9, s0 = r0 & 511, h = k0 >> 6;
                gb = Xp + (((size_t)(b * 8 + h)) * 512 + s0) * 64; rstr = 64;
            }
            lb = &Xs[buf][w][0];
        } else {
            gb = ((w == 2) ? Yhp : Ylp) + (size_t)c0 * 512 + k0; rstr = 512;
            lb = &Ys[buf][w - 2][0];
        }
        #pragma unroll
        for (int j = 0; j < 8; ++j)
            glds16(gb + (size_t)(j * 8 + rloc) * rstr + cp * 8, lb + j * 512);
    };

    auto compute = [&](int buf) {
        #pragma unroll
        for (int ks = 0; ks < 2; ++ks) {
            short8 axh[2], axl[2], byh[2], byl[2];
            const int wm = (w >> 1) * 32, wn = (w & 1) * 32;
            #pragma unroll
            for (int t = 0; t < 2; ++t) {
                int row = wm + t * 16 + c;
                int off = row * 64 + (((ks * 4 + g) ^ (row & 7)) * 8);
                axh[t] = *(const short8*)&Xs[buf][0][off];
                axl[t] = *(const short8*)&Xs[buf][1][off];
                row = wn + t * 16 + c;
                off = row * 64 + (((ks * 4 + g) ^ (row & 7)) * 8);
                byh[t] = *(const short8*)&Ys[buf][0][off];
                byl[t] = *(const short8*)&Ys[buf][1][off];
            }
            #pragma unroll
            for (int tm = 0; tm < 2; ++tm)
                #pragma unroll
                for (int tn = 0; tn < 2; ++tn) {
                    acc[tm][tn] = MFMA_BF16(axh[tm], byh[tn], acc[tm][tn]);
                    acc[tm][tn] = MFMA_BF16(axl[tm], byh[tn], acc[tm][tn]);
                    acc[tm][tn] = MFMA_BF16(axh[tm], byl[tn], acc[tm][tn]);
                }
        }
    };

    stage(0, 0);
    __syncthreads();
    for (int kt = 0; kt < 8; ++kt) {
        if (kt < 7) stage(kt + 1, (kt + 1) & 1);
        compute(kt & 1);
        __syncthreads();
    }

    const int wm = (w >> 1) * 32, wn = (w & 1) * 32;
    if (OM == 0) {
        #pragma unroll
        for (int tn = 0; tn < 2; ++tn) {
            const int gc = c0 + wn + tn * 16 + c;
            const float bv = bias[gc];
            #pragma unroll
            for (int tm = 0; tm < 2; ++tm)
                #pragma unroll
                for (int i = 0; i < 4; ++i) {
                    const int gr = r0 + wm + tm * 16 + g * 4 + i;
                    outF[(size_t)gr * 512 + gc] = acc[tm][tn][i] + bv;
                }
        }
    } else if (OM == 2) {
        #pragma unroll
        for (int tn = 0; tn < 2; ++tn) {
            const int gc = c0 + wn + tn * 16 + c;
            const int h = gc >> 6, dk = gc & 63;
            const float bv = bias[gc];
            #pragma unroll
            for (int tm = 0; tm < 2; ++tm)
                #pragma unroll
                for (int i = 0; i < 4; ++i) {
                    const int gr = r0 + wm + tm * 16 + g * 4 + i;
                    const int b = gr >> 9, s = gr & 511;
                    const float v = (acc[tm][tn][i] + bv) * scale;
                    const unsigned hb = bf16_rne(v);
                    const size_t a = (((size_t)(b * 8 + h)) * 512 + s) * 64 + dk;
                    ohp[a] = (ushort)hb;
                    olp[a] = (ushort)bf16_rne(v - bf16f(hb));
                }
        }
    } else { // OM == 3: V^T, hi plane only
        #pragma unroll
        for (int tm = 0; tm < 2; ++tm)
            #pragma unroll
            for (int i = 0; i < 4; ++i) {
                const int gr = r0 + wm + tm * 16 + g * 4 + i;
                const int h = gr >> 6, dk = gr & 63;
                const float bv = bias[gr];
                #pragma unroll
                for (int tn = 0; tn < 2; ++tn) {
                    const int gc = c0 + wn + tn * 16 + c;
                    const int b = gc >> 9, s = gc & 511;
                    const float v = acc[tm][tn][i] + bv;
                    const size_t a = (((size_t)(b * 8 + h)) * 64 + dk) * 512 + s;
                    ohp[a] = (ushort)bf16_rne(v);
                }
            }
    }
}

// ---------------------------------------------------------------------------
// MFMA flash attention, lane-local softmax (S^T = mfma(K,Q), permuted keys).
// R9 changes vs R8 (passing):
//  - T14 async-stage: ALL staging is reg-staged (10 uint4/thread loaded one
//    tile AHEAD, ds_write after the barrier) -> the stage barrier no longer
//    drains HBM latency; it hides under the previous tile's compute.
//    Global reads are linear; key-permutation + XOR swizzle applied on the
//    ds_write side via the inverse key map.
//  - Usm aliases Rsm (dead after U-MFMAs; extra barrier after U+S MFMAs
//    guards cross-wave Rsm reads). LDS 51 -> 40 KB -> 4 blocks/CU, and
//    1024 blocks = exactly one occupancy round.
// ---------------------------------------------------------------------------
__global__ __launch_bounds__(256, 4)
void attn_mfma(const ushort* __restrict__ Qhp, const ushort* __restrict__ Qlp,
               const ushort* __restrict__ Khp, const ushort* __restrict__ Klp,
               const ushort* __restrict__ Vhp, const ushort* __restrict__ Rg,
               float* __restrict__ Op0, float* __restrict__ Op1,
               float2* __restrict__ Ml0, float2* __restrict__ Ml1) {
    __shared__ ushort Ksm[2][64 * 64];   // 16 KB, key rows PERMUTED (inv map on write)
    __shared__ ushort Vsm[64 * 64];      //  8 KB [dk][key] (V^T)
    __shared__ ushort Rsm[128 * 64];     // 16 KB rel band; REUSED as Usm after U-MFMAs

    const int tid  = threadIdx.x;
    const int w    = tid >> 6;
    const int lane = tid & 63;
    const int g    = lane >> 4;
    const int c    = lane & 15;
    const int bh   = blockIdx.y;
    const int h    = bh & 7;
    const int z    = blockIdx.z;
    const int qwb  = blockIdx.x * 64;
    const int qw   = qwb + w * 16;

    ushort* Usm = &Rsm[w * 1376];        // 16 rows x 86 per wave; 4*1376 <= 8192

    float* __restrict__ Op = z ? Op1 : Op0;
    float2* __restrict__ Ml = z ? Ml1 : Ml0;

    const ushort* KhB = Khp + (size_t)bh * 512 * 64;
    const ushort* KlB = Klp + (size_t)bh * 512 * 64;
    const ushort* VhB = Vhp + (size_t)bh * 64 * 512;
    const ushort* RgH = Rg + (size_t)h * 1152 * 64;

    // staging registers: 10 x 16B per thread (2560 chunks per tile total)
    uint4 rv[10];
    auto issue = [&](int kt) {
        const int k0 = kt * 64;
        const int rbase = k0 - qwb + 512;   // padded rel band base, in [64, 960]
        #pragma unroll
        for (int j = 0; j < 10; ++j) {
            const int cd = j * 256 + tid;
            const ushort* src;
            if (j < 2) {
                const int c2 = cd;                       // Kh chunks 0..511
                src = &KhB[(size_t)(k0 + (c2 >> 3)) * 64 + (c2 & 7) * 8];
            } else if (j < 4) {
                const int c2 = cd - 512;                 // Kl chunks
                src = &KlB[(size_t)(k0 + (c2 >> 3)) * 64 + (c2 & 7) * 8];
            } else if (j < 6) {
                const int c2 = cd - 1024;                // V^T chunks
                src = &VhB[(size_t)(c2 >> 3) * 512 + k0 + (c2 & 7) * 8];
            } else {
                const int c2 = cd - 1536;                // rel band, 128 rows
                src = &RgH[(size_t)(rbase + (c2 >> 3)) * 64 + (c2 & 7) * 8];
            }
            rv[j] = *(const uint4*)src;
        }
    };
    auto commit = [&]() {
        #pragma unroll
        for (int j = 0; j < 10; ++j) {
            const int cd = j * 256 + tid;
            if (j < 4) {
                const int p = j >> 1;
                const int c2 = cd & 511;
                const int krow = c2 >> 3, cc = c2 & 7;
                // inverse of key(lrow)=32(t&1)+8(q>>2)+4(t>>1)+(q&3):
                const int lrow = ((krow & 32) >> 1) | ((krow & 4) << 3)
                               | ((krow & 24) >> 1) | (krow & 3);
                *(uint4*)&Ksm[p][lrow * 64 + ((cc ^ (lrow & 7)) << 3)] = rv[j];
            } else if (j < 6) {
                const int c2 = cd - 1024;
                const int row = c2 >> 3, cc = c2 & 7;
                *(uint4*)&Vsm[row * 64 + ((cc ^ (row & 7)) << 3)] = rv[j];
            } else {
                const int c2 = cd - 1536;
                const int row = c2 >> 3, cc = c2 & 7;
                *(uint4*)&Rsm[row * 64 + ((cc ^ (row & 7)) << 3)] = rv[j];
            }
        }
    };

    short8 qfh[2], qfl[2];
    issue(z * 4);                         // first tile's loads in flight ASAP
    #pragma unroll
    for (int ks = 0; ks < 2; ++ks) {
        const size_t qi = ((size_t)bh * 512 + qw + c) * 64 + ks * 32 + g * 8;
        qfh[ks] = *(const short8*)&Qhp[qi];
        qfl[ks] = *(const short8*)&Qlp[qi];
    }

    const f32x4 fz = {0.f, 0.f, 0.f, 0.f};
    f32x4 o[4] = {fz, fz, fz, fz};      // O^T: row d = 16dt+4g+i, col q = c
    float m = -INFINITY, l = 0.f;

    for (int kt = z * 4; kt < z * 4 + 4; ++kt) {
        __syncthreads();                  // A: prev tile fully consumed
        commit();                         // regs -> LDS (waits its own vmcnt)
        if (kt + 1 < z * 4 + 4) issue(kt + 1);   // prefetch next tile
        __syncthreads();                  // B: LDS visible

        // ---- U tiles: U[q_slot][delta] (1-term) from LDS rel band ----
        f32x4 u[5];
        #pragma unroll
        for (int ut = 0; ut < 5; ++ut) u[ut] = fz;
        #pragma unroll
        for (int ks = 0; ks < 2; ++ks)
            #pragma unroll
            for (int ut = 0; ut < 5; ++ut) {
                const int rl = 48 - 16 * w + c + ut * 16;
                const short8 rf = *(const short8*)
                    &Rsm[rl * 64 + (((ks * 4 + g) ^ (c & 7)) << 3)];
                u[ut] = MFMA_BF16(qfh[ks], rf, u[ut]);
            }

        // ---- S^T tiles: mfma(A=K permuted rows, B=Q), 3-term split ----
        f32x4 st[4];
        #pragma unroll
        for (int tc = 0; tc < 4; ++tc) st[tc] = fz;
        #pragma unroll
        for (int ks = 0; ks < 2; ++ks)
            #pragma unroll
            for (int tc = 0; tc < 4; ++tc) {
                const int row = tc * 16 + c;
                const int chv = ((ks * 4 + g) ^ (row & 7)) * 8;
                const short8 kh8 = *(const short8*)&Ksm[0][row * 64 + chv];
                const short8 kl8 = *(const short8*)&Ksm[1][row * 64 + chv];
                st[tc] = MFMA_BF16(kh8, qfh[ks], st[tc]);
                st[tc] = MFMA_BF16(kh8, qfl[ks], st[tc]);
                st[tc] = MFMA_BF16(kl8, qfh[ks], st[tc]);
            }

        __syncthreads();                  // C: all waves done reading Rsm

        // ---- U frag -> Usm (aliases Rsm space, own-wave region only) ----
        #pragma unroll
        for (int ut = 0; ut < 5; ++ut)
            #pragma unroll
            for (int i = 0; i < 4; ++i)
                Usm[(g * 4 + i) * 86 + c + ut * 16] = (ushort)bf16_rne(u[ut][i]);

        asm volatile("s_waitcnt lgkmcnt(0)" ::: "memory");  // U writes visible

        // ---- bias add (scalar LDS reads, direct delta indexing) ----
        #pragma unroll
        for (int tc = 0; tc < 4; ++tc)
            #pragma unroll
            for (int i = 0; i < 4; ++i) {
                const int key = ((tc & 1) << 5) + 8 * g + ((tc >> 1) << 2) + i;
                st[tc][i] += bf16f(Usm[c * 85 + key + 15]);
            }

        // ---- lane-local online softmax ----
        float tm = fmaxf(fmaxf(st[0][0], st[0][1]), fmaxf(st[0][2], st[0][3]));
        #pragma unroll
        for (int tc = 1; tc < 4; ++tc) {
            const float t2 = fmaxf(fmaxf(st[tc][0], st[tc][1]),
                                   fmaxf(st[tc][2], st[tc][3]));
            tm = fmaxf(tm, t2);
        }
        tm = fmaxf(tm, __shfl_xor(tm, 16));
        tm = fmaxf(tm, __shfl_xor(tm, 32));
        const float mn = fmaxf(m, tm);
        const float corr = __expf(m - mn);
        m = mn;
        l *= corr;
        #pragma unroll
        for (int dt = 0; dt < 4; ++dt) o[dt] *= corr;

        uint pk[4][2];
        #pragma unroll
        for (int tc = 0; tc < 4; ++tc) {
            const float p0 = __expf(st[tc][0] - mn);
            const float p1 = __expf(st[tc][1] - mn);
            const float p2 = __expf(st[tc][2] - mn);
            const float p3 = __expf(st[tc][3] - mn);
            l += (p0 + p1) + (p2 + p3);
            pk[tc][0] = bf16_rne(p0) | (bf16_rne(p1) << 16);
            pk[tc][1] = bf16_rne(p2) | (bf16_rne(p3) << 16);
        }

        // ---- PV: O^T += mfma(A=V^T, B=P^T); B-frag is lane-local ----
        #pragma unroll
        for (int ks = 0; ks < 2; ++ks) {
            union { uint u4[4]; short8 s8; } pb;
            pb.u4[0] = pk[ks][0];
            pb.u4[1] = pk[ks][1];
            pb.u4[2] = pk[ks + 2][0];
            pb.u4[3] = pk[ks + 2][1];
            #pragma unroll
            for (int dt = 0; dt < 4; ++dt) {
                const int row = dt * 16 + c;
                const int chv = ((ks * 4 + g) ^ (row & 7)) * 8;
                const short8 vh8 = *(const short8*)&Vsm[row * 64 + chv];
                o[dt] = MFMA_BF16(vh8, pb.s8, o[dt]);
            }
        }
    }

    // ---- epilogue: reduce l over g-groups, store O^T partial + (m,l) ----
    float lt = l;
    lt += __shfl_xor(lt, 16);
    lt += __shfl_xor(lt, 32);
    if (lane < 16) Ml[(size_t)bh * 512 + qw + c] = make_float2(m, lt);
    #pragma unroll
    for (int dt = 0; dt < 4; ++dt)
        #pragma unroll
        for (int i = 0; i < 4; ++i)
            Op[((size_t)bh * 64 + dt * 16 + g * 4 + i) * 512 + qw + c] = o[dt][i];
}

// ---------------------------------------------------------------------------
// merge split-K halves, transpose O^T -> (b,h,s,dk), emit split-bf16 O planes
// ---------------------------------------------------------------------------
__global__ __launch_bounds__(256)
void attn_combine(const float* __restrict__ Op0, const float* __restrict__ Op1,
                  const float2* __restrict__ Ml0, const float2* __restrict__ Ml1,
                  ushort* __restrict__ Oh, ushort* __restrict__ Ol) {
    __shared__ float L0[64][67];
    __shared__ float L1[64][67];
    const int t = threadIdx.x;
    const int bh = blockIdx.y;
    const int s0 = blockIdx.x * 64;
    #pragma unroll
    for (int j = 0; j < 4; ++j) {
        const int d = (t >> 4) + j * 16;
        const int c4 = (t & 15) * 4;
        const size_t ga = ((size_t)bh * 64 + d) * 512 + s0 + c4;
        *(float4*)&L0[d][c4] = *(const float4*)&Op0[ga];
        *(float4*)&L1[d][c4] = *(const float4*)&Op1[ga];
    }
    __syncthreads();
    const int sl = t >> 2;
    const int d0 = (t & 3) * 16;
    const float2 a = Ml0[(size_t)bh * 512 + s0 + sl];
    const float2 b = Ml1[(size_t)bh * 512 + s0 + sl];
    const float mm = fmaxf(a.x, b.x);
    float w0 = __expf(a.x - mm), w1 = __expf(b.x - mm);
    const float inv = 1.0f / (a.y * w0 + b.y * w1);
    w0 *= inv; w1 *= inv;
    const size_t ob = ((size_t)bh * 512 + s0 + sl) * 64 + d0;
    #pragma unroll
    for (int q = 0; q < 4; ++q) {
        unsigned hb[4], lb4[4];
        #pragma unroll
        for (int e = 0; e < 4; ++e) {
            const int dd = q * 4 + e;
            const float v = L0[d0 + dd][sl] * w0 + L1[d0 + dd][sl] * w1;
            hb[e] = bf16_rne(v);
            lb4[e] = bf16_rne(v - bf16f(hb[e]));
        }
        *(uint2*)&Oh[ob + q * 4] = make_uint2(hb[0] | (hb[1] << 16), hb[2] | (hb[3] << 16));
        *(uint2*)&Ol[ob + q * 4] = make_uint2(lb4[0] | (lb4[1] << 16), lb4[2] | (lb4[3] << 16));
    }
}

// ---------------------------------------------------------------------------
extern "C" void kernel_launch(void* const* d_in, const int* in_sizes, int n_in,
                              void* d_out, int out_size, void* d_ws, size_t ws_size,
                              hipStream_t stream) {
    const float* x   = (const float*)d_in[0];
    const float* Wq  = (const float*)d_in[1];
    const float* bq  = (const float*)d_in[2];
    const float* Wk  = (const float*)d_in[3];
    const float* bk  = (const float*)d_in[4];
    const float* Wv  = (const float*)d_in[5];
    const float* bv  = (const float*)d_in[6];
    const float* Wo  = (const float*)d_in[7];
    const float* bo  = (const float*)d_in[8];
    const float* rel = (const float*)d_in[9];
    float* out = (float*)d_out;

    const size_t NP = (size_t)B_ * H_ * S_ * DK_;   // 2,097,152
    const size_t WP = (size_t)D_ * D_;              //   262,144
    ushort* Xh  = (ushort*)d_ws;
    ushort* Xl  = Xh + NP;
    ushort* Wqh = Xl + NP;
    ushort* Wql = Wqh + WP;
    ushort* Wkh = Wql + WP;
    ushort* Wkl = Wkh + WP;
    ushort* Wvh = Wkl + WP;
    ushort* Wvl = Wvh + WP;
    ushort* Woh = Wvl + WP;
    ushort* Wol = Woh + WP;
    ushort* Qh  = Wol + WP;
    ushort* Ql  = Qh + NP;
    ushort* Kh  = Ql + NP;
    ushort* Kl  = Kh + NP;
    ushort* Vh  = Kl + NP;
    ushort* Rg  = Vh + NP;                    // 589,824 ushorts
    float*  Op1 = (float*)(Rg + 589824);      // NP floats
    float2* Ml0 = (float2*)(Op1 + NP);        // 32768 float2
    float2* Ml1 = Ml0 + 32768;
    float*  Op0 = (float*)d_ws;               // overlays Xh,Xl (dead after proj)

    conv_pl<<<3072, 256, 0, stream>>>(x, Wq, Wk, Wv, Wo,
                                      Xh, Xl, Wqh, Wql, Wkh, Wkl, Wvh, Wvl, Woh, Wol);
    conv_rel<<<1152, 256, 0, stream>>>(rel, Rg);

    // Q and K projections fused via grid.z; K scaled by 1/8 at the source
    gemm_mfma<0, 2><<<dim3(8, 64, 2), 256, 0, stream>>>(
        Xh, Xl, Wqh, Wql, Wkh, Wkl, bq, bk, 1.0f, 0.125f,
        nullptr, Qh, Ql, Kh, Kl);
    // V projection, operand-swapped -> V^T hi plane
    gemm_mfma<0, 3><<<dim3(64, 8, 1), 256, 0, stream>>>(
        Wvh, Wvl, Xh, Xl, nullptr, nullptr, bv, nullptr, 1.0f, 1.0f,
        nullptr, Vh, nullptr, nullptr, nullptr);

    // split-K attention: O^T partials (Op0 overlays X planes, now dead)
    attn_mfma<<<dim3(8, 64, 2), 256, 0, stream>>>(
        Qh, Ql, Kh, Kl, Vh, Rg, Op0, Op1, Ml0, Ml1);

    // combine + transpose -> O planes (overlay Kh,Kl, dead after attn)
    attn_combine<<<dim3(8, 64), 256, 0, stream>>>(Op0, Op1, Ml0, Ml1, Kh, Kl);

    // output projection reads O planes (blocked layout), writes fp32
    gemm_mfma<1, 0><<<dim3(8, 64, 1), 256, 0, stream>>>(
        Kh, Kl, Woh, Wol, nullptr, nullptr, bo, nullptr, 1.0f, 1.0f,
        out, nullptr, nullptr, nullptr, nullptr);
}

// Round 10
// 99.229 us; speedup vs baseline: 1.3368x; 1.3368x over previous
//
#include <hip/hip_runtime.h>
#include <math.h>

#define B_  8
#define S_  512
#define D_  512
#define H_  8
#define DK_ 64

typedef __attribute__((ext_vector_type(8))) short short8;
typedef __attribute__((ext_vector_type(4))) float f32x4;

#define MFMA_BF16(a, b, c) __builtin_amdgcn_mfma_f32_16x16x32_bf16(a, b, c, 0, 0, 0)

__device__ __forceinline__ unsigned bf16_rne(float x) {
    unsigned u = __float_as_uint(x);
    return (u + 0x7FFFu + ((u >> 16) & 1u)) >> 16;
}
__device__ __forceinline__ float bf16f(unsigned h) { return __uint_as_float(h << 16); }

// async global->LDS, 16B per lane; LDS dest wave-uniform (base + lane*16)
__device__ __forceinline__ void glds16(const ushort* g, ushort* l) {
    __builtin_amdgcn_global_load_lds(
        (const __attribute__((address_space(1))) unsigned int*)g,
        (__attribute__((address_space(3))) unsigned int*)l,
        16, 0, 0);
}

// ---------------------------------------------------------------------------
// fp32 -> split-bf16 planes for x, the four weights, AND the rel table
// (conv_rel fused). grid = 2048 (x) + 1024 (W) + 1152 (rel) = 4224 blocks.
// ---------------------------------------------------------------------------
__global__ __launch_bounds__(256)
void conv_pl(const float* __restrict__ x,
             const float* __restrict__ wq, const float* __restrict__ wk,
             const float* __restrict__ wv, const float* __restrict__ wo,
             const float* __restrict__ rel,
             ushort* __restrict__ Xh, ushort* __restrict__ Xl,
             ushort* __restrict__ Wqh, ushort* __restrict__ Wql,
             ushort* __restrict__ Wkh, ushort* __restrict__ Wkl,
             ushort* __restrict__ Wvh, ushort* __restrict__ Wvl,
             ushort* __restrict__ Woh, ushort* __restrict__ Wol,
             ushort* __restrict__ Rg) {
    const int bid = blockIdx.x;
    if (bid >= 3072) {   // rel table -> padded per-head bf16 Rg[8][1152][64]
        const int idx = (bid - 3072) * 256 + threadIdx.x;
        const int d2 = idx & 31;
        const int rr = (idx >> 5) % 1152;
        const int h  = idx / (1152 * 32);
        unsigned v0 = 0, v1 = 0;
        if (rr >= 64 && rr < 64 + 1023) {
            const float* s = &rel[(size_t)(rr - 64) * 512 + h * 64 + d2 * 2];
            v0 = bf16_rne(s[0]); v1 = bf16_rne(s[1]);
        }
        *(uint*)&Rg[((size_t)h * 1152 + rr) * 64 + d2 * 2] = v0 | (v1 << 16);
        return;
    }
    const float* src; ushort* dh; ushort* dl; int i4;
    if (bid < 2048) {
        src = x; dh = Xh; dl = Xl; i4 = bid * 256 + threadIdx.x;
    } else {
        const int r = bid - 2048;
        const int wsel = r >> 8;
        src = (wsel == 0) ? wq : (wsel == 1) ? wk : (wsel == 2) ? wv : wo;
        dh  = (wsel == 0) ? Wqh : (wsel == 1) ? Wkh : (wsel == 2) ? Wvh : Woh;
        dl  = (wsel == 0) ? Wql : (wsel == 1) ? Wkl : (wsel == 2) ? Wvl : Wol;
        i4 = (r & 255) * 256 + threadIdx.x;
    }
    const float4 v = ((const float4*)src)[i4];
    unsigned h[4], l[4];
    const float* vp = &v.x;
    #pragma unroll
    for (int j = 0; j < 4; ++j) { h[j] = bf16_rne(vp[j]); l[j] = bf16_rne(vp[j] - bf16f(h[j])); }
    ((uint2*)dh)[i4] = make_uint2(h[0] | (h[1] << 16), h[2] | (h[3] << 16));
    ((uint2*)dl)[i4] = make_uint2(l[0] | (l[1] << 16), l[2] | (l[3] << 16));
}

// ---------------------------------------------------------------------------
// Split-bf16 MFMA GEMM: D = X . Y^T (+bias)*scale, K=512, tile 64x64, 4 waves.
// XB: 0 = X row-major; 1 = X planes in (b,h,s,dk) blocked layout
// OM: 0 = fp32 row-major out; 2 = split planes (b,h,s,dk), lo-plane skipped
//     when olp==nullptr; 3 = V^T hi-plane only
// ---------------------------------------------------------------------------
template<int XB, int OM>
__global__ __launch_bounds__(256, 2)
void gemm_mfma(const ushort* __restrict__ Xhp, const ushort* __restrict__ Xlp,
               const ushort* __restrict__ Yh0, const ushort* __restrict__ Yl0,
               const ushort* __restrict__ Yh1, const ushort* __restrict__ Yl1,
               const float* __restrict__ bias0, const float* __restrict__ bias1,
               float scale0, float scale1,
               float* __restrict__ outF,
               ushort* __restrict__ oh0, ushort* __restrict__ ol0,
               ushort* __restrict__ oh1, ushort* __restrict__ ol1) {
    __shared__ ushort Xs[2][2][64 * 64];
    __shared__ ushort Ys[2][2][64 * 64];

    const int z = blockIdx.z;
    const ushort* Yhp = z ? Yh1 : Yh0;
    const ushort* Ylp = z ? Yl1 : Yl0;
    const float*  bias = z ? bias1 : bias0;
    const float   scale = z ? scale1 : scale0;
    ushort* ohp = z ? oh1 : oh0;
    ushort* olp = z ? ol1 : ol0;

    const int tid = threadIdx.x;
    const int w = tid >> 6, lane = tid & 63;
    const int g = lane >> 4, c = lane & 15;
    const int rloc = lane >> 3, cc8 = lane & 7;
    const int cp = cc8 ^ rloc;
    const int r0 = blockIdx.y * 64;
    const int c0 = blockIdx.x * 64;

    const f32x4 fz = {0.f, 0.f, 0.f, 0.f};
    f32x4 acc[2][2] = {{fz, fz}, {fz, fz}};

    auto stage = [&](int kt, int buf) {
        const int k0 = kt * 64;
        const ushort* gb; ushort* lb; size_t rstr;
        if (w < 2) {
            const ushort* Xp = (w == 1) ? Xlp : Xhp;
            if (XB == 0) { gb = Xp + (size_t)r0 * 512 + k0; rstr = 512; }
            else {
                const int b = r0 >> 9, s0 = r0 & 511, h = k0 >> 6;
                gb = Xp + (((size_t)(b * 8 + h)) * 512 + s0) * 64; rstr = 64;
            }
            lb = &Xs[buf][w][0];
        } else {
            gb = ((w == 2) ? Yhp : Ylp) + (size_t)c0 * 512 + k0; rstr = 512;
            lb = &Ys[buf][w - 2][0];
        }
        #pragma unroll
        for (int j = 0; j < 8; ++j)
            glds16(gb + (size_t)(j * 8 + rloc) * rstr + cp * 8, lb + j * 512);
    };

    auto compute = [&](int buf) {
        #pragma unroll
        for (int ks = 0; ks < 2; ++ks) {
            short8 axh[2], axl[2], byh[2], byl[2];
            const int wm = (w >> 1) * 32, wn = (w & 1) * 32;
            #pragma unroll
            for (int t = 0; t < 2; ++t) {
                int row = wm + t * 16 + c;
                int off = row * 64 + (((ks * 4 + g) ^ (row & 7)) * 8);
                axh[t] = *(const short8*)&Xs[buf][0][off];
                axl[t] = *(const short8*)&Xs[buf][1][off];
                row = wn + t * 16 + c;
                off = row * 64 + (((ks * 4 + g) ^ (row & 7)) * 8);
                byh[t] = *(const short8*)&Ys[buf][0][off];
                byl[t] = *(const short8*)&Ys[buf][1][off];
            }
            #pragma unroll
            for (int tm = 0; tm < 2; ++tm)
                #pragma unroll
                for (int tn = 0; tn < 2; ++tn) {
                    acc[tm][tn] = MFMA_BF16(axh[tm], byh[tn], acc[tm][tn]);
                    acc[tm][tn] = MFMA_BF16(axl[tm], byh[tn], acc[tm][tn]);
                    acc[tm][tn] = MFMA_BF16(axh[tm], byl[tn], acc[tm][tn]);
                }
        }
    };

    stage(0, 0);
    __syncthreads();
    for (int kt = 0; kt < 8; ++kt) {
        if (kt < 7) stage(kt + 1, (kt + 1) & 1);
        compute(kt & 1);
        __syncthreads();
    }

    const int wm = (w >> 1) * 32, wn = (w & 1) * 32;
    if (OM == 0) {
        #pragma unroll
        for (int tn = 0; tn < 2; ++tn) {
            const int gc = c0 + wn + tn * 16 + c;
            const float bv = bias[gc];
            #pragma unroll
            for (int tm = 0; tm < 2; ++tm)
                #pragma unroll
                for (int i = 0; i < 4; ++i) {
                    const int gr = r0 + wm + tm * 16 + g * 4 + i;
                    outF[(size_t)gr * 512 + gc] = acc[tm][tn][i] + bv;
                }
        }
    } else if (OM == 2) {
        #pragma unroll
        for (int tn = 0; tn < 2; ++tn) {
            const int gc = c0 + wn + tn * 16 + c;
            const int h = gc >> 6, dk = gc & 63;
            const float bv = bias[gc];
            #pragma unroll
            for (int tm = 0; tm < 2; ++tm)
                #pragma unroll
                for (int i = 0; i < 4; ++i) {
                    const int gr = r0 + wm + tm * 16 + g * 4 + i;
                    const int b = gr >> 9, s = gr & 511;
                    const float v = (acc[tm][tn][i] + bv) * scale;
                    const unsigned hb = bf16_rne(v);
                    const size_t a = (((size_t)(b * 8 + h)) * 512 + s) * 64 + dk;
                    ohp[a] = (ushort)hb;
                    if (olp) olp[a] = (ushort)bf16_rne(v - bf16f(hb));
                }
        }
    } else { // OM == 3: V^T, hi plane only
        #pragma unroll
        for (int tm = 0; tm < 2; ++tm)
            #pragma unroll
            for (int i = 0; i < 4; ++i) {
                const int gr = r0 + wm + tm * 16 + g * 4 + i;
                const int h = gr >> 6, dk = gr & 63;
                const float bv = bias[gr];
                #pragma unroll
                for (int tn = 0; tn < 2; ++tn) {
                    const int gc = c0 + wn + tn * 16 + c;
                    const int b = gc >> 9, s = gc & 511;
                    const float v = acc[tm][tn][i] + bv;
                    const size_t a = (((size_t)(b * 8 + h)) * 64 + dk) * 512 + s;
                    ohp[a] = (ushort)bf16_rne(v);
                }
            }
    }
}

// ---------------------------------------------------------------------------
// MFMA flash attention, lane-local softmax (S^T = mfma(K,Q), permuted keys).
// R10 vs R8 (passing): (1) 2-term S — K lo-plane dropped (error ~1e-3 on S,
// well under threshold); Ksm is single-plane, staged by waves 0/1.
// (2) T14-lite: the 4-chunk rel band is prefetched one tile ahead into 4
// uint4 regs (16 VGPRs only — R9's 40-reg version spilled); barrier B is a
// RAW s_barrier with counted vmcnt(4) so the prefetch loads stay in flight
// (T4). Last tile drains vmcnt(0). launch_bounds (256,3) for reg headroom.
// ---------------------------------------------------------------------------
__global__ __launch_bounds__(256, 3)
void attn_mfma(const ushort* __restrict__ Qhp, const ushort* __restrict__ Qlp,
               const ushort* __restrict__ Khp, const ushort* __restrict__ Vhp,
               const ushort* __restrict__ Rg,
               float* __restrict__ Op0, float* __restrict__ Op1,
               float2* __restrict__ Ml0, float2* __restrict__ Ml1) {
    __shared__ ushort Ksm[64 * 64];      //  8 KB, key rows PERMUTED, hi plane
    __shared__ ushort Vsm[64 * 64];      //  8 KB [dk][key] (V^T)
    __shared__ ushort Rsm[128 * 64];     // 16 KB rel band, chunk-swizzled
    __shared__ ushort Usm[4][16 * 86];   // 11 KB per-wave bias rows

    const int tid  = threadIdx.x;
    const int w    = tid >> 6;
    const int lane = tid & 63;
    const int g    = lane >> 4;
    const int c    = lane & 15;
    const int rloc = lane >> 3, cc8 = lane & 7;
    const int bh   = blockIdx.y;
    const int h    = bh & 7;
    const int z    = blockIdx.z;
    const int qwb  = blockIdx.x * 64;
    const int qw   = qwb + w * 16;

    float* __restrict__ Op = z ? Op1 : Op0;
    float2* __restrict__ Ml = z ? Ml1 : Ml0;

    const ushort* KhB = Khp + (size_t)bh * 512 * 64;
    const ushort* VhB = Vhp + (size_t)bh * 64 * 512;
    const ushort* RgH = Rg + (size_t)h * 1152 * 64;

    // rel-band prefetch registers: 4 x 16B per thread (1024 chunks/tile)
    uint4 rv[4];
    auto issue_rel = [&](int kt) {
        const int rbase = kt * 64 - qwb + 512;   // in [64, 960]
        #pragma unroll
        for (int j = 0; j < 4; ++j) {
            const int cd = j * 256 + tid, row = cd >> 3, cc = cd & 7;
            rv[j] = *(const uint4*)&RgH[(size_t)(rbase + row) * 64 + cc * 8];
        }
    };

    issue_rel(z * 4);
    short8 qfh[2], qfl[2];
    #pragma unroll
    for (int ks = 0; ks < 2; ++ks) {
        const size_t qi = ((size_t)bh * 512 + qw + c) * 64 + ks * 32 + g * 8;
        qfh[ks] = *(const short8*)&Qhp[qi];
        qfl[ks] = *(const short8*)&Qlp[qi];
    }

    const f32x4 fz = {0.f, 0.f, 0.f, 0.f};
    f32x4 o[4] = {fz, fz, fz, fz};      // O^T: row d = 16dt+4g+i, col q = c
    float m = -INFINITY, l = 0.f;

    for (int kt = z * 4; kt < z * 4 + 4; ++kt) {
        const int k0 = kt * 64;
        __syncthreads();                 // A: prev tile fully consumed

        // ---- commit prefetched rel band (swizzled ds_write) ----
        #pragma unroll
        for (int j = 0; j < 4; ++j) {
            const int cd = j * 256 + tid, row = cd >> 3, cc = cd & 7;
            *(uint4*)&Rsm[row * 64 + ((cc ^ (row & 7)) << 3)] = rv[j];
        }
        // ---- stage Kh (key-permuted) / V^T via glds, 4 per wave ----
        if (w < 2) {
            ushort* lb = &Ksm[w * 32 * 64];
            #pragma unroll
            for (int j = 0; j < 4; ++j) {
                const int row = w * 32 + j * 8 + rloc;
                const int tcq = row >> 4, cq = row & 15;
                const int key = ((tcq & 1) << 5) + ((cq >> 2) << 3)
                              + ((tcq >> 1) << 2) + (cq & 3);
                glds16(KhB + (size_t)(k0 + key) * 64 + ((cc8 ^ rloc) << 3),
                       lb + j * 512);
            }
        } else {
            const ushort* gb = VhB + k0 + (size_t)(w - 2) * 32 * 512;
            ushort* lb = &Vsm[(w - 2) * 32 * 64];
            #pragma unroll
            for (int j = 0; j < 4; ++j)
                glds16(gb + (size_t)(j * 8 + rloc) * 512 + ((cc8 ^ rloc) << 3),
                       lb + j * 512);
        }

        // ---- B: raw barrier; drain glds + ds_writes, keep prefetch alive ----
        if (kt + 1 < z * 4 + 4) {
            issue_rel(kt + 1);           // 4 loads in flight across the barrier
            asm volatile("s_waitcnt vmcnt(4) lgkmcnt(0)" ::: "memory");
        } else {
            asm volatile("s_waitcnt vmcnt(0) lgkmcnt(0)" ::: "memory");
        }
        __builtin_amdgcn_s_barrier();

        // ---- U tiles: U[q][delta] (1-term) from LDS rel band ----
        f32x4 u[5];
        #pragma unroll
        for (int ut = 0; ut < 5; ++ut) u[ut] = fz;
        #pragma unroll
        for (int ks = 0; ks < 2; ++ks)
            #pragma unroll
            for (int ut = 0; ut < 5; ++ut) {
                const int rl = 48 - 16 * w + c + ut * 16;
                const short8 rf = *(const short8*)
                    &Rsm[rl * 64 + (((ks * 4 + g) ^ (c & 7)) << 3)];
                u[ut] = MFMA_BF16(qfh[ks], rf, u[ut]);
            }
        #pragma unroll
        for (int ut = 0; ut < 5; ++ut)
            #pragma unroll
            for (int i = 0; i < 4; ++i)
                Usm[w][(g * 4 + i) * 86 + c + ut * 16] = (ushort)bf16_rne(u[ut][i]);

        // ---- S^T tiles: mfma(A=Kh permuted rows, B=Q), 2-term split ----
        f32x4 st[4];
        #pragma unroll
        for (int tc = 0; tc < 4; ++tc) st[tc] = fz;
        #pragma unroll
        for (int ks = 0; ks < 2; ++ks)
            #pragma unroll
            for (int tc = 0; tc < 4; ++tc) {
                const int row = tc * 16 + c;
                const int chv = ((ks * 4 + g) ^ (row & 7)) * 8;
                const short8 kh8 = *(const short8*)&Ksm[row * 64 + chv];
                st[tc] = MFMA_BF16(kh8, qfh[ks], st[tc]);
                st[tc] = MFMA_BF16(kh8, qfl[ks], st[tc]);
            }

        asm volatile("s_waitcnt lgkmcnt(0)" ::: "memory");  // U writes visible

        // ---- bias add (scalar LDS reads, direct delta indexing) ----
        #pragma unroll
        for (int tc = 0; tc < 4; ++tc)
            #pragma unroll
            for (int i = 0; i < 4; ++i) {
                const int key = ((tc & 1) << 5) + 8 * g + ((tc >> 1) << 2) + i;
                st[tc][i] += bf16f(Usm[w][c * 85 + key + 15]);
            }

        // ---- lane-local online softmax ----
        float tm = fmaxf(fmaxf(st[0][0], st[0][1]), fmaxf(st[0][2], st[0][3]));
        #pragma unroll
        for (int tc = 1; tc < 4; ++tc) {
            const float t2 = fmaxf(fmaxf(st[tc][0], st[tc][1]),
                                   fmaxf(st[tc][2], st[tc][3]));
            tm = fmaxf(tm, t2);
        }
        tm = fmaxf(tm, __shfl_xor(tm, 16));
        tm = fmaxf(tm, __shfl_xor(tm, 32));
        const float mn = fmaxf(m, tm);
        const float corr = __expf(m - mn);
        m = mn;
        l *= corr;
        #pragma unroll
        for (int dt = 0; dt < 4; ++dt) o[dt] *= corr;

        uint pk[4][2];
        #pragma unroll
        for (int tc = 0; tc < 4; ++tc) {
            const float p0 = __expf(st[tc][0] - mn);
            const float p1 = __expf(st[tc][1] - mn);
            const float p2 = __expf(st[tc][2] - mn);
            const float p3 = __expf(st[tc][3] - mn);
            l += (p0 + p1) + (p2 + p3);
            pk[tc][0] = bf16_rne(p0) | (bf16_rne(p1) << 16);
            pk[tc][1] = bf16_rne(p2) | (bf16_rne(p3) << 16);
        }

        // ---- PV: O^T += mfma(A=V^T, B=P^T); B-frag is lane-local ----
        #pragma unroll
        for (int ks = 0; ks < 2; ++ks) {
            union { uint u4[4]; short8 s8; } pb;
            pb.u4[0] = pk[ks][0];
            pb.u4[1] = pk[ks][1];
            pb.u4[2] = pk[ks + 2][0];
            pb.u4[3] = pk[ks + 2][1];
            #pragma unroll
            for (int dt = 0; dt < 4; ++dt) {
                const int row = dt * 16 + c;
                const int chv = ((ks * 4 + g) ^ (row & 7)) * 8;
                const short8 vh8 = *(const short8*)&Vsm[row * 64 + chv];
                o[dt] = MFMA_BF16(vh8, pb.s8, o[dt]);
            }
        }
    }

    // ---- epilogue: reduce l over g-groups, store O^T partial + (m,l) ----
    float lt = l;
    lt += __shfl_xor(lt, 16);
    lt += __shfl_xor(lt, 32);
    if (lane < 16) Ml[(size_t)bh * 512 + qw + c] = make_float2(m, lt);
    #pragma unroll
    for (int dt = 0; dt < 4; ++dt)
        #pragma unroll
        for (int i = 0; i < 4; ++i)
            Op[((size_t)bh * 64 + dt * 16 + g * 4 + i) * 512 + qw + c] = o[dt][i];
}

// ---------------------------------------------------------------------------
// merge split-K halves, transpose O^T -> (b,h,s,dk), emit split-bf16 O planes
// ---------------------------------------------------------------------------
__global__ __launch_bounds__(256)
void attn_combine(const float* __restrict__ Op0, const float* __restrict__ Op1,
                  const float2* __restrict__ Ml0, const float2* __restrict__ Ml1,
                  ushort* __restrict__ Oh, ushort* __restrict__ Ol) {
    __shared__ float L0[64][67];
    __shared__ float L1[64][67];
    const int t = threadIdx.x;
    const int bh = blockIdx.y;
    const int s0 = blockIdx.x * 64;
    #pragma unroll
    for (int j = 0; j < 4; ++j) {
        const int d = (t >> 4) + j * 16;
        const int c4 = (t & 15) * 4;
        const size_t ga = ((size_t)bh * 64 + d) * 512 + s0 + c4;
        *(float4*)&L0[d][c4] = *(const float4*)&Op0[ga];
        *(float4*)&L1[d][c4] = *(const float4*)&Op1[ga];
    }
    __syncthreads();
    const int sl = t >> 2;
    const int d0 = (t & 3) * 16;
    const float2 a = Ml0[(size_t)bh * 512 + s0 + sl];
    const float2 b = Ml1[(size_t)bh * 512 + s0 + sl];
    const float mm = fmaxf(a.x, b.x);
    float w0 = __expf(a.x - mm), w1 = __expf(b.x - mm);
    const float inv = 1.0f / (a.y * w0 + b.y * w1);
    w0 *= inv; w1 *= inv;
    const size_t ob = ((size_t)bh * 512 + s0 + sl) * 64 + d0;
    #pragma unroll
    for (int q = 0; q < 4; ++q) {
        unsigned hb[4], lb4[4];
        #pragma unroll
        for (int e = 0; e < 4; ++e) {
            const int dd = q * 4 + e;
            const float v = L0[d0 + dd][sl] * w0 + L1[d0 + dd][sl] * w1;
            hb[e] = bf16_rne(v);
            lb4[e] = bf16_rne(v - bf16f(hb[e]));
        }
        *(uint2*)&Oh[ob + q * 4] = make_uint2(hb[0] | (hb[1] << 16), hb[2] | (hb[3] << 16));
        *(uint2*)&Ol[ob + q * 4] = make_uint2(lb4[0] | (lb4[1] << 16), lb4[2] | (lb4[3] << 16));
    }
}

// ---------------------------------------------------------------------------
extern "C" void kernel_launch(void* const* d_in, const int* in_sizes, int n_in,
                              void* d_out, int out_size, void* d_ws, size_t ws_size,
                              hipStream_t stream) {
    const float* x   = (const float*)d_in[0];
    const float* Wq  = (const float*)d_in[1];
    const float* bq  = (const float*)d_in[2];
    const float* Wk  = (const float*)d_in[3];
    const float* bk  = (const float*)d_in[4];
    const float* Wv  = (const float*)d_in[5];
    const float* bv  = (const float*)d_in[6];
    const float* Wo  = (const float*)d_in[7];
    const float* bo  = (const float*)d_in[8];
    const float* rel = (const float*)d_in[9];
    float* out = (float*)d_out;

    const size_t NP = (size_t)B_ * H_ * S_ * DK_;   // 2,097,152
    const size_t WP = (size_t)D_ * D_;              //   262,144
    ushort* Xh  = (ushort*)d_ws;
    ushort* Xl  = Xh + NP;
    ushort* Wqh = Xl + NP;
    ushort* Wql = Wqh + WP;
    ushort* Wkh = Wql + WP;
    ushort* Wkl = Wkh + WP;
    ushort* Wvh = Wkl + WP;
    ushort* Wvl = Wvh + WP;
    ushort* Woh = Wvl + WP;
    ushort* Wol = Woh + WP;
    ushort* Qh  = Wol + WP;
    ushort* Ql  = Qh + NP;
    ushort* Kh  = Ql + NP;
    ushort* Kl  = Kh + NP;                    // unused by attn now (kept for layout)
    ushort* Vh  = Kl + NP;
    ushort* Rg  = Vh + NP;                    // 589,824 ushorts
    float*  Op1 = (float*)(Rg + 589824);      // NP floats
    float2* Ml0 = (float2*)(Op1 + NP);        // 32768 float2
    float2* Ml1 = Ml0 + 32768;
    float*  Op0 = (float*)d_ws;               // overlays Xh,Xl (dead after proj)

    conv_pl<<<4224, 256, 0, stream>>>(x, Wq, Wk, Wv, Wo, rel,
                                      Xh, Xl, Wqh, Wql, Wkh, Wkl, Wvh, Wvl, Woh, Wol, Rg);

    // Q and K projections fused via grid.z; K scaled by 1/8, K lo-plane skipped
    gemm_mfma<0, 2><<<dim3(8, 64, 2), 256, 0, stream>>>(
        Xh, Xl, Wqh, Wql, Wkh, Wkl, bq, bk, 1.0f, 0.125f,
        nullptr, Qh, Ql, Kh, nullptr);
    // V projection, operand-swapped -> V^T hi plane
    gemm_mfma<0, 3><<<dim3(64, 8, 1), 256, 0, stream>>>(
        Wvh, Wvl, Xh, Xl, nullptr, nullptr, bv, nullptr, 1.0f, 1.0f,
        nullptr, Vh, nullptr, nullptr, nullptr);

    // split-K attention: O^T partials (Op0 overlays X planes, now dead)
    attn_mfma<<<dim3(8, 64, 2), 256, 0, stream>>>(
        Qh, Ql, Kh, Vh, Rg, Op0, Op1, Ml0, Ml1);

    // combine + transpose -> O planes (overlay Kh,Kl region, dead after attn)
    attn_combine<<<dim3(8, 64), 256, 0, stream>>>(Op0, Op1, Ml0, Ml1, Kh, Kl);

    // output projection reads O planes (blocked layout), writes fp32
    gemm_mfma<1, 0><<<dim3(8, 64, 1), 256, 0, stream>>>(
        Kh, Kl, Woh, Wol, nullptr, nullptr, bo, nullptr, 1.0f, 1.0f,
        out, nullptr, nullptr, nullptr, nullptr);
}

// Round 11
// 95.797 us; speedup vs baseline: 1.3847x; 1.0358x over previous
//
#include <hip/hip_runtime.h>
#include <math.h>

#define B_  8
#define S_  512
#define D_  512
#define H_  8
#define DK_ 64

typedef __attribute__((ext_vector_type(8))) short short8;
typedef __attribute__((ext_vector_type(4))) float f32x4;

#define MFMA_BF16(a, b, c) __builtin_amdgcn_mfma_f32_16x16x32_bf16(a, b, c, 0, 0, 0)

__device__ __forceinline__ unsigned bf16_rne(float x) {
    unsigned u = __float_as_uint(x);
    return (u + 0x7FFFu + ((u >> 16) & 1u)) >> 16;
}
__device__ __forceinline__ float bf16f(unsigned h) { return __uint_as_float(h << 16); }

// async global->LDS, 16B per lane; LDS dest wave-uniform (base + lane*16)
__device__ __forceinline__ void glds16(const ushort* g, ushort* l) {
    __builtin_amdgcn_global_load_lds(
        (const __attribute__((address_space(1))) unsigned int*)g,
        (__attribute__((address_space(3))) unsigned int*)l,
        16, 0, 0);
}

// ---------------------------------------------------------------------------
// fp32 -> split-bf16 planes for x, the four weights, AND the rel table
// (conv_rel fused). grid = 2048 (x) + 1024 (W) + 1152 (rel) = 4224 blocks.
// ---------------------------------------------------------------------------
__global__ __launch_bounds__(256)
void conv_pl(const float* __restrict__ x,
             const float* __restrict__ wq, const float* __restrict__ wk,
             const float* __restrict__ wv, const float* __restrict__ wo,
             const float* __restrict__ rel,
             ushort* __restrict__ Xh, ushort* __restrict__ Xl,
             ushort* __restrict__ Wqh, ushort* __restrict__ Wql,
             ushort* __restrict__ Wkh, ushort* __restrict__ Wkl,
             ushort* __restrict__ Wvh, ushort* __restrict__ Wvl,
             ushort* __restrict__ Woh, ushort* __restrict__ Wol,
             ushort* __restrict__ Rg) {
    const int bid = blockIdx.x;
    if (bid >= 3072) {   // rel table -> padded per-head bf16 Rg[8][1152][64]
        const int idx = (bid - 3072) * 256 + threadIdx.x;
        const int d2 = idx & 31;
        const int rr = (idx >> 5) % 1152;
        const int h  = idx / (1152 * 32);
        unsigned v0 = 0, v1 = 0;
        if (rr >= 64 && rr < 64 + 1023) {
            const float* s = &rel[(size_t)(rr - 64) * 512 + h * 64 + d2 * 2];
            v0 = bf16_rne(s[0]); v1 = bf16_rne(s[1]);
        }
        *(uint*)&Rg[((size_t)h * 1152 + rr) * 64 + d2 * 2] = v0 | (v1 << 16);
        return;
    }
    const float* src; ushort* dh; ushort* dl; int i4;
    if (bid < 2048) {
        src = x; dh = Xh; dl = Xl; i4 = bid * 256 + threadIdx.x;
    } else {
        const int r = bid - 2048;
        const int wsel = r >> 8;
        src = (wsel == 0) ? wq : (wsel == 1) ? wk : (wsel == 2) ? wv : wo;
        dh  = (wsel == 0) ? Wqh : (wsel == 1) ? Wkh : (wsel == 2) ? Wvh : Woh;
        dl  = (wsel == 0) ? Wql : (wsel == 1) ? Wkl : (wsel == 2) ? Wvl : Wol;
        i4 = (r & 255) * 256 + threadIdx.x;
    }
    const float4 v = ((const float4*)src)[i4];
    unsigned h[4], l[4];
    const float* vp = &v.x;
    #pragma unroll
    for (int j = 0; j < 4; ++j) { h[j] = bf16_rne(vp[j]); l[j] = bf16_rne(vp[j] - bf16f(h[j])); }
    ((uint2*)dh)[i4] = make_uint2(h[0] | (h[1] << 16), h[2] | (h[3] << 16));
    ((uint2*)dl)[i4] = make_uint2(l[0] | (l[1] << 16), l[2] | (l[3] << 16));
}

// ---------------------------------------------------------------------------
// Split-bf16 MFMA GEMM: D = X . Y^T (+bias)*scale, K=512, tile 64x64, 4 waves.
// XB: 0 = X row-major; 1 = X planes in (b,h,s,dk) blocked layout
// OM: 0 = fp32 row-major out; 2 = split planes (b,h,s,dk), lo-plane skipped
//     when olp==nullptr; 3 = V^T hi-plane only
// ---------------------------------------------------------------------------
template<int XB, int OM>
__global__ __launch_bounds__(256, 2)
void gemm_mfma(const ushort* __restrict__ Xhp, const ushort* __restrict__ Xlp,
               const ushort* __restrict__ Yh0, const ushort* __restrict__ Yl0,
               const ushort* __restrict__ Yh1, const ushort* __restrict__ Yl1,
               const float* __restrict__ bias0, const float* __restrict__ bias1,
               float scale0, float scale1,
               float* __restrict__ outF,
               ushort* __restrict__ oh0, ushort* __restrict__ ol0,
               ushort* __restrict__ oh1, ushort* __restrict__ ol1) {
    __shared__ ushort Xs[2][2][64 * 64];
    __shared__ ushort Ys[2][2][64 * 64];

    const int z = blockIdx.z;
    const ushort* Yhp = z ? Yh1 : Yh0;
    const ushort* Ylp = z ? Yl1 : Yl0;
    const float*  bias = z ? bias1 : bias0;
    const float   scale = z ? scale1 : scale0;
    ushort* ohp = z ? oh1 : oh0;
    ushort* olp = z ? ol1 : ol0;

    const int tid = threadIdx.x;
    const int w = tid >> 6, lane = tid & 63;
    const int g = lane >> 4, c = lane & 15;
    const int rloc = lane >> 3, cc8 = lane & 7;
    const int cp = cc8 ^ rloc;
    const int r0 = blockIdx.y * 64;
    const int c0 = blockIdx.x * 64;

    const f32x4 fz = {0.f, 0.f, 0.f, 0.f};
    f32x4 acc[2][2] = {{fz, fz}, {fz, fz}};

    auto stage = [&](int kt, int buf) {
        const int k0 = kt * 64;
        const ushort* gb; ushort* lb; size_t rstr;
        if (w < 2) {
            const ushort* Xp = (w == 1) ? Xlp : Xhp;
            if (XB == 0) { gb = Xp + (size_t)r0 * 512 + k0; rstr = 512; }
            else {
                const int b = r0 >> 9, s0 = r0 & 511, h = k0 >> 6;
                gb = Xp + (((size_t)(b * 8 + h)) * 512 + s0) * 64; rstr = 64;
            }
            lb = &Xs[buf][w][0];
        } else {
            gb = ((w == 2) ? Yhp : Ylp) + (size_t)c0 * 512 + k0; rstr = 512;
            lb = &Ys[buf][w - 2][0];
        }
        #pragma unroll
        for (int j = 0; j < 8; ++j)
            glds16(gb + (size_t)(j * 8 + rloc) * rstr + cp * 8, lb + j * 512);
    };

    auto compute = [&](int buf) {
        #pragma unroll
        for (int ks = 0; ks < 2; ++ks) {
            short8 axh[2], axl[2], byh[2], byl[2];
            const int wm = (w >> 1) * 32, wn = (w & 1) * 32;
            #pragma unroll
            for (int t = 0; t < 2; ++t) {
                int row = wm + t * 16 + c;
                int off = row * 64 + (((ks * 4 + g) ^ (row & 7)) * 8);
                axh[t] = *(const short8*)&Xs[buf][0][off];
                axl[t] = *(const short8*)&Xs[buf][1][off];
                row = wn + t * 16 + c;
                off = row * 64 + (((ks * 4 + g) ^ (row & 7)) * 8);
                byh[t] = *(const short8*)&Ys[buf][0][off];
                byl[t] = *(const short8*)&Ys[buf][1][off];
            }
            #pragma unroll
            for (int tm = 0; tm < 2; ++tm)
                #pragma unroll
                for (int tn = 0; tn < 2; ++tn) {
                    acc[tm][tn] = MFMA_BF16(axh[tm], byh[tn], acc[tm][tn]);
                    acc[tm][tn] = MFMA_BF16(axl[tm], byh[tn], acc[tm][tn]);
                    acc[tm][tn] = MFMA_BF16(axh[tm], byl[tn], acc[tm][tn]);
                }
        }
    };

    stage(0, 0);
    __syncthreads();
    for (int kt = 0; kt < 8; ++kt) {
        if (kt < 7) stage(kt + 1, (kt + 1) & 1);
        compute(kt & 1);
        __syncthreads();
    }

    const int wm = (w >> 1) * 32, wn = (w & 1) * 32;
    if (OM == 0) {
        #pragma unroll
        for (int tn = 0; tn < 2; ++tn) {
            const int gc = c0 + wn + tn * 16 + c;
            const float bv = bias[gc];
            #pragma unroll
            for (int tm = 0; tm < 2; ++tm)
                #pragma unroll
                for (int i = 0; i < 4; ++i) {
                    const int gr = r0 + wm + tm * 16 + g * 4 + i;
                    outF[(size_t)gr * 512 + gc] = acc[tm][tn][i] + bv;
                }
        }
    } else if (OM == 2) {
        #pragma unroll
        for (int tn = 0; tn < 2; ++tn) {
            const int gc = c0 + wn + tn * 16 + c;
            const int h = gc >> 6, dk = gc & 63;
            const float bv = bias[gc];
            #pragma unroll
            for (int tm = 0; tm < 2; ++tm)
                #pragma unroll
                for (int i = 0; i < 4; ++i) {
                    const int gr = r0 + wm + tm * 16 + g * 4 + i;
                    const int b = gr >> 9, s = gr & 511;
                    const float v = (acc[tm][tn][i] + bv) * scale;
                    const unsigned hb = bf16_rne(v);
                    const size_t a = (((size_t)(b * 8 + h)) * 512 + s) * 64 + dk;
                    ohp[a] = (ushort)hb;
                    if (olp) olp[a] = (ushort)bf16_rne(v - bf16f(hb));
                }
        }
    } else { // OM == 3: V^T, hi plane only
        #pragma unroll
        for (int tm = 0; tm < 2; ++tm)
            #pragma unroll
            for (int i = 0; i < 4; ++i) {
                const int gr = r0 + wm + tm * 16 + g * 4 + i;
                const int h = gr >> 6, dk = gr & 63;
                const float bv = bias[gr];
                #pragma unroll
                for (int tn = 0; tn < 2; ++tn) {
                    const int gc = c0 + wn + tn * 16 + c;
                    const int b = gc >> 9, s = gc & 511;
                    const float v = acc[tm][tn][i] + bv;
                    const size_t a = (((size_t)(b * 8 + h)) * 64 + dk) * 512 + s;
                    ohp[a] = (ushort)bf16_rne(v);
                }
            }
    }
}

// ---------------------------------------------------------------------------
// MFMA flash attention, lane-local softmax (S^T = mfma(K,Q), permuted keys).
// R11 vs R10 (passing): Usm aliases Rsm (Rsm dead after U-MFMAs; barrier C
// after the S-MFMA cluster guards cross-wave Rsm reads). LDS 44 -> 32 KB ->
// capacity 5 blocks/CU >= the 4 needed -> ALL 1024 blocks co-resident in one
// round (R10 ran 3/CU + a 1/CU straggler round = 20% occupancy).
// ---------------------------------------------------------------------------
__global__ __launch_bounds__(256, 4)
void attn_mfma(const ushort* __restrict__ Qhp, const ushort* __restrict__ Qlp,
               const ushort* __restrict__ Khp, const ushort* __restrict__ Vhp,
               const ushort* __restrict__ Rg,
               float* __restrict__ Op0, float* __restrict__ Op1,
               float2* __restrict__ Ml0, float2* __restrict__ Ml1) {
    __shared__ ushort Ksm[64 * 64];      //  8 KB, key rows PERMUTED, hi plane
    __shared__ ushort Vsm[64 * 64];      //  8 KB [dk][key] (V^T)
    __shared__ ushort Rsm[128 * 64];     // 16 KB rel band; REUSED as Usm after U-MFMAs

    const int tid  = threadIdx.x;
    const int w    = tid >> 6;
    const int lane = tid & 63;
    const int g    = lane >> 4;
    const int c    = lane & 15;
    const int rloc = lane >> 3, cc8 = lane & 7;
    const int bh   = blockIdx.y;
    const int h    = bh & 7;
    const int z    = blockIdx.z;
    const int qwb  = blockIdx.x * 64;
    const int qw   = qwb + w * 16;

    ushort* Usm = &Rsm[w * 1376];        // per-wave 16x86 region; 4*1376 <= 8192

    float* __restrict__ Op = z ? Op1 : Op0;
    float2* __restrict__ Ml = z ? Ml1 : Ml0;

    const ushort* KhB = Khp + (size_t)bh * 512 * 64;
    const ushort* VhB = Vhp + (size_t)bh * 64 * 512;
    const ushort* RgH = Rg + (size_t)h * 1152 * 64;

    // rel-band prefetch registers: 4 x 16B per thread (1024 chunks/tile)
    uint4 rv[4];
    auto issue_rel = [&](int kt) {
        const int rbase = kt * 64 - qwb + 512;   // in [64, 960]
        #pragma unroll
        for (int j = 0; j < 4; ++j) {
            const int cd = j * 256 + tid, row = cd >> 3, cc = cd & 7;
            rv[j] = *(const uint4*)&RgH[(size_t)(rbase + row) * 64 + cc * 8];
        }
    };

    issue_rel(z * 4);
    short8 qfh[2], qfl[2];
    #pragma unroll
    for (int ks = 0; ks < 2; ++ks) {
        const size_t qi = ((size_t)bh * 512 + qw + c) * 64 + ks * 32 + g * 8;
        qfh[ks] = *(const short8*)&Qhp[qi];
        qfl[ks] = *(const short8*)&Qlp[qi];
    }

    const f32x4 fz = {0.f, 0.f, 0.f, 0.f};
    f32x4 o[4] = {fz, fz, fz, fz};      // O^T: row d = 16dt+4g+i, col q = c
    float m = -INFINITY, l = 0.f;

    for (int kt = z * 4; kt < z * 4 + 4; ++kt) {
        const int k0 = kt * 64;
        __syncthreads();                 // A: prev tile fully consumed

        // ---- commit prefetched rel band (swizzled ds_write) ----
        #pragma unroll
        for (int j = 0; j < 4; ++j) {
            const int cd = j * 256 + tid, row = cd >> 3, cc = cd & 7;
            *(uint4*)&Rsm[row * 64 + ((cc ^ (row & 7)) << 3)] = rv[j];
        }
        // ---- stage Kh (key-permuted) / V^T via glds, 4 per wave ----
        if (w < 2) {
            ushort* lb = &Ksm[w * 32 * 64];
            #pragma unroll
            for (int j = 0; j < 4; ++j) {
                const int row = w * 32 + j * 8 + rloc;
                const int tcq = row >> 4, cq = row & 15;
                const int key = ((tcq & 1) << 5) + ((cq >> 2) << 3)
                              + ((tcq >> 1) << 2) + (cq & 3);
                glds16(KhB + (size_t)(k0 + key) * 64 + ((cc8 ^ rloc) << 3),
                       lb + j * 512);
            }
        } else {
            const ushort* gb = VhB + k0 + (size_t)(w - 2) * 32 * 512;
            ushort* lb = &Vsm[(w - 2) * 32 * 64];
            #pragma unroll
            for (int j = 0; j < 4; ++j)
                glds16(gb + (size_t)(j * 8 + rloc) * 512 + ((cc8 ^ rloc) << 3),
                       lb + j * 512);
        }

        // ---- B: raw barrier; drain glds + ds_writes, keep prefetch alive ----
        if (kt + 1 < z * 4 + 4) {
            issue_rel(kt + 1);           // 4 loads in flight across the barrier
            asm volatile("s_waitcnt vmcnt(4) lgkmcnt(0)" ::: "memory");
        } else {
            asm volatile("s_waitcnt vmcnt(0) lgkmcnt(0)" ::: "memory");
        }
        __builtin_amdgcn_s_barrier();

        // ---- U tiles: U[q][delta] (1-term) from LDS rel band ----
        f32x4 u[5];
        #pragma unroll
        for (int ut = 0; ut < 5; ++ut) u[ut] = fz;
        #pragma unroll
        for (int ks = 0; ks < 2; ++ks)
            #pragma unroll
            for (int ut = 0; ut < 5; ++ut) {
                const int rl = 48 - 16 * w + c + ut * 16;
                const short8 rf = *(const short8*)
                    &Rsm[rl * 64 + (((ks * 4 + g) ^ (c & 7)) << 3)];
                u[ut] = MFMA_BF16(qfh[ks], rf, u[ut]);
            }

        // ---- S^T tiles: mfma(A=Kh permuted rows, B=Q), 2-term split ----
        f32x4 st[4];
        #pragma unroll
        for (int tc = 0; tc < 4; ++tc) st[tc] = fz;
        #pragma unroll
        for (int ks = 0; ks < 2; ++ks)
            #pragma unroll
            for (int tc = 0; tc < 4; ++tc) {
                const int row = tc * 16 + c;
                const int chv = ((ks * 4 + g) ^ (row & 7)) * 8;
                const short8 kh8 = *(const short8*)&Ksm[row * 64 + chv];
                st[tc] = MFMA_BF16(kh8, qfh[ks], st[tc]);
                st[tc] = MFMA_BF16(kh8, qfl[ks], st[tc]);
            }

        __syncthreads();                 // C: all waves done reading Rsm

        // ---- U frag -> Usm (aliases Rsm, own-wave region only) ----
        #pragma unroll
        for (int ut = 0; ut < 5; ++ut)
            #pragma unroll
            for (int i = 0; i < 4; ++i)
                Usm[(g * 4 + i) * 86 + c + ut * 16] = (ushort)bf16_rne(u[ut][i]);

        asm volatile("s_waitcnt lgkmcnt(0)" ::: "memory");  // U writes visible

        // ---- bias add (scalar LDS reads, direct delta indexing) ----
        #pragma unroll
        for (int tc = 0; tc < 4; ++tc)
            #pragma unroll
            for (int i = 0; i < 4; ++i) {
                const int key = ((tc & 1) << 5) + 8 * g + ((tc >> 1) << 2) + i;
                st[tc][i] += bf16f(Usm[c * 85 + key + 15]);
            }

        // ---- lane-local online softmax ----
        float tm = fmaxf(fmaxf(st[0][0], st[0][1]), fmaxf(st[0][2], st[0][3]));
        #pragma unroll
        for (int tc = 1; tc < 4; ++tc) {
            const float t2 = fmaxf(fmaxf(st[tc][0], st[tc][1]),
                                   fmaxf(st[tc][2], st[tc][3]));
            tm = fmaxf(tm, t2);
        }
        tm = fmaxf(tm, __shfl_xor(tm, 16));
        tm = fmaxf(tm, __shfl_xor(tm, 32));
        const float mn = fmaxf(m, tm);
        const float corr = __expf(m - mn);
        m = mn;
        l *= corr;
        #pragma unroll
        for (int dt = 0; dt < 4; ++dt) o[dt] *= corr;

        uint pk[4][2];
        #pragma unroll
        for (int tc = 0; tc < 4; ++tc) {
            const float p0 = __expf(st[tc][0] - mn);
            const float p1 = __expf(st[tc][1] - mn);
            const float p2 = __expf(st[tc][2] - mn);
            const float p3 = __expf(st[tc][3] - mn);
            l += (p0 + p1) + (p2 + p3);
            pk[tc][0] = bf16_rne(p0) | (bf16_rne(p1) << 16);
            pk[tc][1] = bf16_rne(p2) | (bf16_rne(p3) << 16);
        }

        // ---- PV: O^T += mfma(A=V^T, B=P^T); B-frag is lane-local ----
        #pragma unroll
        for (int ks = 0; ks < 2; ++ks) {
            union { uint u4[4]; short8 s8; } pb;
            pb.u4[0] = pk[ks][0];
            pb.u4[1] = pk[ks][1];
            pb.u4[2] = pk[ks + 2][0];
            pb.u4[3] = pk[ks + 2][1];
            #pragma unroll
            for (int dt = 0; dt < 4; ++dt) {
                const int row = dt * 16 + c;
                const int chv = ((ks * 4 + g) ^ (row & 7)) * 8;
                const short8 vh8 = *(const short8*)&Vsm[row * 64 + chv];
                o[dt] = MFMA_BF16(vh8, pb.s8, o[dt]);
            }
        }
    }

    // ---- epilogue: reduce l over g-groups, store O^T partial + (m,l) ----
    float lt = l;
    lt += __shfl_xor(lt, 16);
    lt += __shfl_xor(lt, 32);
    if (lane < 16) Ml[(size_t)bh * 512 + qw + c] = make_float2(m, lt);
    #pragma unroll
    for (int dt = 0; dt < 4; ++dt)
        #pragma unroll
        for (int i = 0; i < 4; ++i)
            Op[((size_t)bh * 64 + dt * 16 + g * 4 + i) * 512 + qw + c] = o[dt][i];
}

// ---------------------------------------------------------------------------
// merge split-K halves, transpose O^T -> (b,h,s,dk), emit split-bf16 O planes
// ---------------------------------------------------------------------------
__global__ __launch_bounds__(256)
void attn_combine(const float* __restrict__ Op0, const float* __restrict__ Op1,
                  const float2* __restrict__ Ml0, const float2* __restrict__ Ml1,
                  ushort* __restrict__ Oh, ushort* __restrict__ Ol) {
    __shared__ float L0[64][67];
    __shared__ float L1[64][67];
    const int t = threadIdx.x;
    const int bh = blockIdx.y;
    const int s0 = blockIdx.x * 64;
    #pragma unroll
    for (int j = 0; j < 4; ++j) {
        const int d = (t >> 4) + j * 16;
        const int c4 = (t & 15) * 4;
        const size_t ga = ((size_t)bh * 64 + d) * 512 + s0 + c4;
        *(float4*)&L0[d][c4] = *(const float4*)&Op0[ga];
        *(float4*)&L1[d][c4] = *(const float4*)&Op1[ga];
    }
    __syncthreads();
    const int sl = t >> 2;
    const int d0 = (t & 3) * 16;
    const float2 a = Ml0[(size_t)bh * 512 + s0 + sl];
    const float2 b = Ml1[(size_t)bh * 512 + s0 + sl];
    const float mm = fmaxf(a.x, b.x);
    float w0 = __expf(a.x - mm), w1 = __expf(b.x - mm);
    const float inv = 1.0f / (a.y * w0 + b.y * w1);
    w0 *= inv; w1 *= inv;
    const size_t ob = ((size_t)bh * 512 + s0 + sl) * 64 + d0;
    #pragma unroll
    for (int q = 0; q < 4; ++q) {
        unsigned hb[4], lb4[4];
        #pragma unroll
        for (int e = 0; e < 4; ++e) {
            const int dd = q * 4 + e;
            const float v = L0[d0 + dd][sl] * w0 + L1[d0 + dd][sl] * w1;
            hb[e] = bf16_rne(v);
            lb4[e] = bf16_rne(v - bf16f(hb[e]));
        }
        *(uint2*)&Oh[ob + q * 4] = make_uint2(hb[0] | (hb[1] << 16), hb[2] | (hb[3] << 16));
        *(uint2*)&Ol[ob + q * 4] = make_uint2(lb4[0] | (lb4[1] << 16), lb4[2] | (lb4[3] << 16));
    }
}

// ---------------------------------------------------------------------------
extern "C" void kernel_launch(void* const* d_in, const int* in_sizes, int n_in,
                              void* d_out, int out_size, void* d_ws, size_t ws_size,
                              hipStream_t stream) {
    const float* x   = (const float*)d_in[0];
    const float* Wq  = (const float*)d_in[1];
    const float* bq  = (const float*)d_in[2];
    const float* Wk  = (const float*)d_in[3];
    const float* bk  = (const float*)d_in[4];
    const float* Wv  = (const float*)d_in[5];
    const float* bv  = (const float*)d_in[6];
    const float* Wo  = (const float*)d_in[7];
    const float* bo  = (const float*)d_in[8];
    const float* rel = (const float*)d_in[9];
    float* out = (float*)d_out;

    const size_t NP = (size_t)B_ * H_ * S_ * DK_;   // 2,097,152
    const size_t WP = (size_t)D_ * D_;              //   262,144
    ushort* Xh  = (ushort*)d_ws;
    ushort* Xl  = Xh + NP;
    ushort* Wqh = Xl + NP;
    ushort* Wql = Wqh + WP;
    ushort* Wkh = Wql + WP;
    ushort* Wkl = Wkh + WP;
    ushort* Wvh = Wkl + WP;
    ushort* Wvl = Wvh + WP;
    ushort* Woh = Wvl + WP;
    ushort* Wol = Woh + WP;
    ushort* Qh  = Wol + WP;
    ushort* Ql  = Qh + NP;
    ushort* Kh  = Ql + NP;
    ushort* Kl  = Kh + NP;                    // unused by attn now (kept for layout)
    ushort* Vh  = Kl + NP;
    ushort* Rg  = Vh + NP;                    // 589,824 ushorts
    float*  Op1 = (float*)(Rg + 589824);      // NP floats
    float2* Ml0 = (float2*)(Op1 + NP);        // 32768 float2
    float2* Ml1 = Ml0 + 32768;
    float*  Op0 = (float*)d_ws;               // overlays Xh,Xl (dead after proj)

    conv_pl<<<4224, 256, 0, stream>>>(x, Wq, Wk, Wv, Wo, rel,
                                      Xh, Xl, Wqh, Wql, Wkh, Wkl, Wvh, Wvl, Woh, Wol, Rg);

    // Q and K projections fused via grid.z; K scaled by 1/8, K lo-plane skipped
    gemm_mfma<0, 2><<<dim3(8, 64, 2), 256, 0, stream>>>(
        Xh, Xl, Wqh, Wql, Wkh, Wkl, bq, bk, 1.0f, 0.125f,
        nullptr, Qh, Ql, Kh, nullptr);
    // V projection, operand-swapped -> V^T hi plane
    gemm_mfma<0, 3><<<dim3(64, 8, 1), 256, 0, stream>>>(
        Wvh, Wvl, Xh, Xl, nullptr, nullptr, bv, nullptr, 1.0f, 1.0f,
        nullptr, Vh, nullptr, nullptr, nullptr);

    // split-K attention: O^T partials (Op0 overlays X planes, now dead)
    attn_mfma<<<dim3(8, 64, 2), 256, 0, stream>>>(
        Qh, Ql, Kh, Vh, Rg, Op0, Op1, Ml0, Ml1);

    // combine + transpose -> O planes (overlay Kh,Kl region, dead after attn)
    attn_combine<<<dim3(8, 64), 256, 0, stream>>>(Op0, Op1, Ml0, Ml1, Kh, Kl);

    // output projection reads O planes (blocked layout), writes fp32
    gemm_mfma<1, 0><<<dim3(8, 64, 1), 256, 0, stream>>>(
        Kh, Kl, Woh, Wol, nullptr, nullptr, bo, nullptr, 1.0f, 1.0f,
        out, nullptr, nullptr, nullptr, nullptr);
}

// Round 12
// 91.690 us; speedup vs baseline: 1.4467x; 1.0448x over previous
//
#include <hip/hip_runtime.h>
#include <math.h>

#define B_  8
#define S_  512
#define D_  512
#define H_  8
#define DK_ 64

typedef __attribute__((ext_vector_type(8))) short short8;
typedef __attribute__((ext_vector_type(4))) float f32x4;

#define MFMA_BF16(a, b, c) __builtin_amdgcn_mfma_f32_16x16x32_bf16(a, b, c, 0, 0, 0)

__device__ __forceinline__ unsigned bf16_rne(float x) {
    unsigned u = __float_as_uint(x);
    return (u + 0x7FFFu + ((u >> 16) & 1u)) >> 16;
}
__device__ __forceinline__ float bf16f(unsigned h) { return __uint_as_float(h << 16); }

// async global->LDS, 16B per lane; LDS dest wave-uniform (base + lane*16)
__device__ __forceinline__ void glds16(const ushort* g, ushort* l) {
    __builtin_amdgcn_global_load_lds(
        (const __attribute__((address_space(1))) unsigned int*)g,
        (__attribute__((address_space(3))) unsigned int*)l,
        16, 0, 0);
}

// ---------------------------------------------------------------------------
// fp32 -> split-bf16 planes for x, the four weights, AND the rel table.
// grid = 2048 (x) + 1024 (W) + 1152 (rel) = 4224 blocks.
// ---------------------------------------------------------------------------
__global__ __launch_bounds__(256)
void conv_pl(const float* __restrict__ x,
             const float* __restrict__ wq, const float* __restrict__ wk,
             const float* __restrict__ wv, const float* __restrict__ wo,
             const float* __restrict__ rel,
             ushort* __restrict__ Xh, ushort* __restrict__ Xl,
             ushort* __restrict__ Wqh, ushort* __restrict__ Wql,
             ushort* __restrict__ Wkh, ushort* __restrict__ Wkl,
             ushort* __restrict__ Wvh, ushort* __restrict__ Wvl,
             ushort* __restrict__ Woh, ushort* __restrict__ Wol,
             ushort* __restrict__ Rg) {
    const int bid = blockIdx.x;
    if (bid >= 3072) {   // rel table -> padded per-head bf16 Rg[8][1152][64]
        const int idx = (bid - 3072) * 256 + threadIdx.x;
        const int d2 = idx & 31;
        const int rr = (idx >> 5) % 1152;
        const int h  = idx / (1152 * 32);
        unsigned v0 = 0, v1 = 0;
        if (rr >= 64 && rr < 64 + 1023) {
            const float* s = &rel[(size_t)(rr - 64) * 512 + h * 64 + d2 * 2];
            v0 = bf16_rne(s[0]); v1 = bf16_rne(s[1]);
        }
        *(uint*)&Rg[((size_t)h * 1152 + rr) * 64 + d2 * 2] = v0 | (v1 << 16);
        return;
    }
    const float* src; ushort* dh; ushort* dl; int i4;
    if (bid < 2048) {
        src = x; dh = Xh; dl = Xl; i4 = bid * 256 + threadIdx.x;
    } else {
        const int r = bid - 2048;
        const int wsel = r >> 8;
        src = (wsel == 0) ? wq : (wsel == 1) ? wk : (wsel == 2) ? wv : wo;
        dh  = (wsel == 0) ? Wqh : (wsel == 1) ? Wkh : (wsel == 2) ? Wvh : Woh;
        dl  = (wsel == 0) ? Wql : (wsel == 1) ? Wkl : (wsel == 2) ? Wvl : Wol;
        i4 = (r & 255) * 256 + threadIdx.x;
    }
    const float4 v = ((const float4*)src)[i4];
    unsigned h[4], l[4];
    const float* vp = &v.x;
    #pragma unroll
    for (int j = 0; j < 4; ++j) { h[j] = bf16_rne(vp[j]); l[j] = bf16_rne(vp[j] - bf16f(h[j])); }
    ((uint2*)dh)[i4] = make_uint2(h[0] | (h[1] << 16), h[2] | (h[3] << 16));
    ((uint2*)dl)[i4] = make_uint2(l[0] | (l[1] << 16), l[2] | (l[3] << 16));
}

// ---------------------------------------------------------------------------
// Split-bf16 MFMA GEMM, R12: 2-TERM (Xh.Bh + Xl.Bh — B-lo plane dropped).
// LDS 48 KB (B single-plane) -> 3 blocks/CU; 16 MFMA per K-step.
// Staging: 24 wave-uniform 1KB segments (Xh 8, Xl 8, Bh 8), 6 per wave.
// XB: 0 = X row-major; 1 = X planes in (b,h,s,dk) blocked layout
// OM: 0 = fp32 row-major out; 2 = split planes (b,h,s,dk), lo skipped if
//     olp==nullptr; 3 = V^T hi-plane only
// ---------------------------------------------------------------------------
template<int XB, int OM>
__global__ __launch_bounds__(256, 3)
void gemm_mfma(const ushort* __restrict__ Xhp, const ushort* __restrict__ Xlp,
               const ushort* __restrict__ Yh0, const ushort* __restrict__ Yl0,
               const ushort* __restrict__ Yh1, const ushort* __restrict__ Yl1,
               const float* __restrict__ bias0, const float* __restrict__ bias1,
               float scale0, float scale1,
               float* __restrict__ outF,
               ushort* __restrict__ oh0, ushort* __restrict__ ol0,
               ushort* __restrict__ oh1, ushort* __restrict__ ol1) {
    __shared__ ushort Xs[2][2][64 * 64];   // 32 KB
    __shared__ ushort Ys[2][64 * 64];      // 16 KB (hi plane only)

    const int z = blockIdx.z;
    const ushort* Yhp = z ? Yh1 : Yh0;
    const float*  bias = z ? bias1 : bias0;
    const float   scale = z ? scale1 : scale0;
    ushort* ohp = z ? oh1 : oh0;
    ushort* olp = z ? ol1 : ol0;

    const int tid = threadIdx.x;
    const int w = tid >> 6, lane = tid & 63;
    const int g = lane >> 4, c = lane & 15;
    const int rloc = lane >> 3, cc8 = lane & 7;
    const int cp = cc8 ^ rloc;
    const int r0 = blockIdx.y * 64;
    const int c0 = blockIdx.x * 64;

    const f32x4 fz = {0.f, 0.f, 0.f, 0.f};
    f32x4 acc[2][2] = {{fz, fz}, {fz, fz}};

    auto stage = [&](int kt, int buf) {
        const int k0 = kt * 64;
        #pragma unroll
        for (int j = 0; j < 6; ++j) {
            const int seg = w * 6 + j;          // 0..23, wave-uniform
            const int p = seg >> 3;             // 0:Xh 1:Xl 2:Yh
            const int rgrp = seg & 7;
            const int row = rgrp * 8 + rloc;
            const ushort* gb;
            if (p == 2) {
                gb = Yhp + (size_t)(c0 + row) * 512 + k0 + cp * 8;
            } else {
                const ushort* Xp = p ? Xlp : Xhp;
                if (XB == 0) {
                    gb = Xp + (size_t)(r0 + row) * 512 + k0 + cp * 8;
                } else {
                    const int b = r0 >> 9, s0 = r0 & 511, hh = k0 >> 6;
                    gb = Xp + (((size_t)(b * 8 + hh)) * 512 + s0 + row) * 64 + cp * 8;
                }
            }
            ushort* lb = (p == 2) ? &Ys[buf][0] : &Xs[buf][p][0];
            glds16(gb, lb + rgrp * 512);
        }
    };

    auto compute = [&](int buf) {
        #pragma unroll
        for (int ks = 0; ks < 2; ++ks) {
            short8 axh[2], axl[2], byh[2];
            const int wm = (w >> 1) * 32, wn = (w & 1) * 32;
            #pragma unroll
            for (int t = 0; t < 2; ++t) {
                int row = wm + t * 16 + c;
                int off = row * 64 + (((ks * 4 + g) ^ (row & 7)) * 8);
                axh[t] = *(const short8*)&Xs[buf][0][off];
                axl[t] = *(const short8*)&Xs[buf][1][off];
                row = wn + t * 16 + c;
                off = row * 64 + (((ks * 4 + g) ^ (row & 7)) * 8);
                byh[t] = *(const short8*)&Ys[buf][off];
            }
            #pragma unroll
            for (int tm = 0; tm < 2; ++tm)
                #pragma unroll
                for (int tn = 0; tn < 2; ++tn) {
                    acc[tm][tn] = MFMA_BF16(axh[tm], byh[tn], acc[tm][tn]);
                    acc[tm][tn] = MFMA_BF16(axl[tm], byh[tn], acc[tm][tn]);
                }
        }
    };

    stage(0, 0);
    __syncthreads();
    for (int kt = 0; kt < 8; ++kt) {
        if (kt < 7) stage(kt + 1, (kt + 1) & 1);
        compute(kt & 1);
        __syncthreads();
    }

    const int wm = (w >> 1) * 32, wn = (w & 1) * 32;
    if (OM == 0) {
        #pragma unroll
        for (int tn = 0; tn < 2; ++tn) {
            const int gc = c0 + wn + tn * 16 + c;
            const float bv = bias[gc];
            #pragma unroll
            for (int tm = 0; tm < 2; ++tm)
                #pragma unroll
                for (int i = 0; i < 4; ++i) {
                    const int gr = r0 + wm + tm * 16 + g * 4 + i;
                    outF[(size_t)gr * 512 + gc] = acc[tm][tn][i] + bv;
                }
        }
    } else if (OM == 2) {
        #pragma unroll
        for (int tn = 0; tn < 2; ++tn) {
            const int gc = c0 + wn + tn * 16 + c;
            const int h = gc >> 6, dk = gc & 63;
            const float bv = bias[gc];
            #pragma unroll
            for (int tm = 0; tm < 2; ++tm)
                #pragma unroll
                for (int i = 0; i < 4; ++i) {
                    const int gr = r0 + wm + tm * 16 + g * 4 + i;
                    const int b = gr >> 9, s = gr & 511;
                    const float v = (acc[tm][tn][i] + bv) * scale;
                    const unsigned hb = bf16_rne(v);
                    const size_t a = (((size_t)(b * 8 + h)) * 512 + s) * 64 + dk;
                    ohp[a] = (ushort)hb;
                    if (olp) olp[a] = (ushort)bf16_rne(v - bf16f(hb));
                }
        }
    } else { // OM == 3: V^T, hi plane only
        #pragma unroll
        for (int tm = 0; tm < 2; ++tm)
            #pragma unroll
            for (int i = 0; i < 4; ++i) {
                const int gr = r0 + wm + tm * 16 + g * 4 + i;
                const int h = gr >> 6, dk = gr & 63;
                const float bv = bias[gr];
                #pragma unroll
                for (int tn = 0; tn < 2; ++tn) {
                    const int gc = c0 + wn + tn * 16 + c;
                    const int b = gc >> 9, s = gc & 511;
                    const float v = acc[tm][tn][i] + bv;
                    const size_t a = (((size_t)(b * 8 + h)) * 64 + dk) * 512 + s;
                    ohp[a] = (ushort)bf16_rne(v);
                }
            }
    }
}

// ---------------------------------------------------------------------------
// MFMA flash attention (unchanged from passing R11): lane-local softmax,
// S^T = mfma(K,Q) with permuted keys, Usm aliases Rsm, 32 KB LDS,
// rel-band prefetch with counted vmcnt across a raw barrier.
// ---------------------------------------------------------------------------
__global__ __launch_bounds__(256, 4)
void attn_mfma(const ushort* __restrict__ Qhp, const ushort* __restrict__ Qlp,
               const ushort* __restrict__ Khp, const ushort* __restrict__ Vhp,
               const ushort* __restrict__ Rg,
               float* __restrict__ Op0, float* __restrict__ Op1,
               float2* __restrict__ Ml0, float2* __restrict__ Ml1) {
    __shared__ ushort Ksm[64 * 64];      //  8 KB, key rows PERMUTED, hi plane
    __shared__ ushort Vsm[64 * 64];      //  8 KB [dk][key] (V^T)
    __shared__ ushort Rsm[128 * 64];     // 16 KB rel band; REUSED as Usm after U-MFMAs

    const int tid  = threadIdx.x;
    const int w    = tid >> 6;
    const int lane = tid & 63;
    const int g    = lane >> 4;
    const int c    = lane & 15;
    const int rloc = lane >> 3, cc8 = lane & 7;
    const int bh   = blockIdx.y;
    const int h    = bh & 7;
    const int z    = blockIdx.z;
    const int qwb  = blockIdx.x * 64;
    const int qw   = qwb + w * 16;

    ushort* Usm = &Rsm[w * 1376];        // per-wave 16x86 region; 4*1376 <= 8192

    float* __restrict__ Op = z ? Op1 : Op0;
    float2* __restrict__ Ml = z ? Ml1 : Ml0;

    const ushort* KhB = Khp + (size_t)bh * 512 * 64;
    const ushort* VhB = Vhp + (size_t)bh * 64 * 512;
    const ushort* RgH = Rg + (size_t)h * 1152 * 64;

    uint4 rv[4];
    auto issue_rel = [&](int kt) {
        const int rbase = kt * 64 - qwb + 512;   // in [64, 960]
        #pragma unroll
        for (int j = 0; j < 4; ++j) {
            const int cd = j * 256 + tid, row = cd >> 3, cc = cd & 7;
            rv[j] = *(const uint4*)&RgH[(size_t)(rbase + row) * 64 + cc * 8];
        }
    };

    issue_rel(z * 4);
    short8 qfh[2], qfl[2];
    #pragma unroll
    for (int ks = 0; ks < 2; ++ks) {
        const size_t qi = ((size_t)bh * 512 + qw + c) * 64 + ks * 32 + g * 8;
        qfh[ks] = *(const short8*)&Qhp[qi];
        qfl[ks] = *(const short8*)&Qlp[qi];
    }

    const f32x4 fz = {0.f, 0.f, 0.f, 0.f};
    f32x4 o[4] = {fz, fz, fz, fz};      // O^T: row d = 16dt+4g+i, col q = c
    float m = -INFINITY, l = 0.f;

    for (int kt = z * 4; kt < z * 4 + 4; ++kt) {
        const int k0 = kt * 64;
        __syncthreads();                 // A: prev tile fully consumed

        // ---- commit prefetched rel band (swizzled ds_write) ----
        #pragma unroll
        for (int j = 0; j < 4; ++j) {
            const int cd = j * 256 + tid, row = cd >> 3, cc = cd & 7;
            *(uint4*)&Rsm[row * 64 + ((cc ^ (row & 7)) << 3)] = rv[j];
        }
        // ---- stage Kh (key-permuted) / V^T via glds, 4 per wave ----
        if (w < 2) {
            ushort* lb = &Ksm[w * 32 * 64];
            #pragma unroll
            for (int j = 0; j < 4; ++j) {
                const int row = w * 32 + j * 8 + rloc;
                const int tcq = row >> 4, cq = row & 15;
                const int key = ((tcq & 1) << 5) + ((cq >> 2) << 3)
                              + ((tcq >> 1) << 2) + (cq & 3);
                glds16(KhB + (size_t)(k0 + key) * 64 + ((cc8 ^ rloc) << 3),
                       lb + j * 512);
            }
        } else {
            const ushort* gb = VhB + k0 + (size_t)(w - 2) * 32 * 512;
            ushort* lb = &Vsm[(w - 2) * 32 * 64];
            #pragma unroll
            for (int j = 0; j < 4; ++j)
                glds16(gb + (size_t)(j * 8 + rloc) * 512 + ((cc8 ^ rloc) << 3),
                       lb + j * 512);
        }

        // ---- B: raw barrier; drain glds + ds_writes, keep prefetch alive ----
        if (kt + 1 < z * 4 + 4) {
            issue_rel(kt + 1);           // 4 loads in flight across the barrier
            asm volatile("s_waitcnt vmcnt(4) lgkmcnt(0)" ::: "memory");
        } else {
            asm volatile("s_waitcnt vmcnt(0) lgkmcnt(0)" ::: "memory");
        }
        __builtin_amdgcn_s_barrier();

        // ---- U tiles: U[q][delta] (1-term) from LDS rel band ----
        f32x4 u[5];
        #pragma unroll
        for (int ut = 0; ut < 5; ++ut) u[ut] = fz;
        #pragma unroll
        for (int ks = 0; ks < 2; ++ks)
            #pragma unroll
            for (int ut = 0; ut < 5; ++ut) {
                const int rl = 48 - 16 * w + c + ut * 16;
                const short8 rf = *(const short8*)
                    &Rsm[rl * 64 + (((ks * 4 + g) ^ (c & 7)) << 3)];
                u[ut] = MFMA_BF16(qfh[ks], rf, u[ut]);
            }

        // ---- S^T tiles: mfma(A=Kh permuted rows, B=Q), 2-term split ----
        f32x4 st[4];
        #pragma unroll
        for (int tc = 0; tc < 4; ++tc) st[tc] = fz;
        #pragma unroll
        for (int ks = 0; ks < 2; ++ks)
            #pragma unroll
            for (int tc = 0; tc < 4; ++tc) {
                const int row = tc * 16 + c;
                const int chv = ((ks * 4 + g) ^ (row & 7)) * 8;
                const short8 kh8 = *(const short8*)&Ksm[row * 64 + chv];
                st[tc] = MFMA_BF16(kh8, qfh[ks], st[tc]);
                st[tc] = MFMA_BF16(kh8, qfl[ks], st[tc]);
            }

        __syncthreads();                 // C: all waves done reading Rsm

        // ---- U frag -> Usm (aliases Rsm, own-wave region only) ----
        #pragma unroll
        for (int ut = 0; ut < 5; ++ut)
            #pragma unroll
            for (int i = 0; i < 4; ++i)
                Usm[(g * 4 + i) * 86 + c + ut * 16] = (ushort)bf16_rne(u[ut][i]);

        asm volatile("s_waitcnt lgkmcnt(0)" ::: "memory");  // U writes visible

        // ---- bias add (scalar LDS reads, direct delta indexing) ----
        #pragma unroll
        for (int tc = 0; tc < 4; ++tc)
            #pragma unroll
            for (int i = 0; i < 4; ++i) {
                const int key = ((tc & 1) << 5) + 8 * g + ((tc >> 1) << 2) + i;
                st[tc][i] += bf16f(Usm[c * 85 + key + 15]);
            }

        // ---- lane-local online softmax ----
        float tm = fmaxf(fmaxf(st[0][0], st[0][1]), fmaxf(st[0][2], st[0][3]));
        #pragma unroll
        for (int tc = 1; tc < 4; ++tc) {
            const float t2 = fmaxf(fmaxf(st[tc][0], st[tc][1]),
                                   fmaxf(st[tc][2], st[tc][3]));
            tm = fmaxf(tm, t2);
        }
        tm = fmaxf(tm, __shfl_xor(tm, 16));
        tm = fmaxf(tm, __shfl_xor(tm, 32));
        const float mn = fmaxf(m, tm);
        const float corr = __expf(m - mn);
        m = mn;
        l *= corr;
        #pragma unroll
        for (int dt = 0; dt < 4; ++dt) o[dt] *= corr;

        uint pk[4][2];
        #pragma unroll
        for (int tc = 0; tc < 4; ++tc) {
            const float p0 = __expf(st[tc][0] - mn);
            const float p1 = __expf(st[tc][1] - mn);
            const float p2 = __expf(st[tc][2] - mn);
            const float p3 = __expf(st[tc][3] - mn);
            l += (p0 + p1) + (p2 + p3);
            pk[tc][0] = bf16_rne(p0) | (bf16_rne(p1) << 16);
            pk[tc][1] = bf16_rne(p2) | (bf16_rne(p3) << 16);
        }

        // ---- PV: O^T += mfma(A=V^T, B=P^T); B-frag is lane-local ----
        #pragma unroll
        for (int ks = 0; ks < 2; ++ks) {
            union { uint u4[4]; short8 s8; } pb;
            pb.u4[0] = pk[ks][0];
            pb.u4[1] = pk[ks][1];
            pb.u4[2] = pk[ks + 2][0];
            pb.u4[3] = pk[ks + 2][1];
            #pragma unroll
            for (int dt = 0; dt < 4; ++dt) {
                const int row = dt * 16 + c;
                const int chv = ((ks * 4 + g) ^ (row & 7)) * 8;
                const short8 vh8 = *(const short8*)&Vsm[row * 64 + chv];
                o[dt] = MFMA_BF16(vh8, pb.s8, o[dt]);
            }
        }
    }

    // ---- epilogue: reduce l over g-groups, store O^T partial + (m,l) ----
    float lt = l;
    lt += __shfl_xor(lt, 16);
    lt += __shfl_xor(lt, 32);
    if (lane < 16) Ml[(size_t)bh * 512 + qw + c] = make_float2(m, lt);
    #pragma unroll
    for (int dt = 0; dt < 4; ++dt)
        #pragma unroll
        for (int i = 0; i < 4; ++i)
            Op[((size_t)bh * 64 + dt * 16 + g * 4 + i) * 512 + qw + c] = o[dt][i];
}

// ---------------------------------------------------------------------------
// merge split-K halves, transpose O^T -> (b,h,s,dk), emit split-bf16 O planes
// ---------------------------------------------------------------------------
__global__ __launch_bounds__(256)
void attn_combine(const float* __restrict__ Op0, const float* __restrict__ Op1,
                  const float2* __restrict__ Ml0, const float2* __restrict__ Ml1,
                  ushort* __restrict__ Oh, ushort* __restrict__ Ol) {
    __shared__ float L0[64][67];
    __shared__ float L1[64][67];
    const int t = threadIdx.x;
    const int bh = blockIdx.y;
    const int s0 = blockIdx.x * 64;
    #pragma unroll
    for (int j = 0; j < 4; ++j) {
        const int d = (t >> 4) + j * 16;
        const int c4 = (t & 15) * 4;
        const size_t ga = ((size_t)bh * 64 + d) * 512 + s0 + c4;
        *(float4*)&L0[d][c4] = *(const float4*)&Op0[ga];
        *(float4*)&L1[d][c4] = *(const float4*)&Op1[ga];
    }
    __syncthreads();
    const int sl = t >> 2;
    const int d0 = (t & 3) * 16;
    const float2 a = Ml0[(size_t)bh * 512 + s0 + sl];
    const float2 b = Ml1[(size_t)bh * 512 + s0 + sl];
    const float mm = fmaxf(a.x, b.x);
    float w0 = __expf(a.x - mm), w1 = __expf(b.x - mm);
    const float inv = 1.0f / (a.y * w0 + b.y * w1);
    w0 *= inv; w1 *= inv;
    const size_t ob = ((size_t)bh * 512 + s0 + sl) * 64 + d0;
    #pragma unroll
    for (int q = 0; q < 4; ++q) {
        unsigned hb[4], lb4[4];
        #pragma unroll
        for (int e = 0; e < 4; ++e) {
            const int dd = q * 4 + e;
            const float v = L0[d0 + dd][sl] * w0 + L1[d0 + dd][sl] * w1;
            hb[e] = bf16_rne(v);
            lb4[e] = bf16_rne(v - bf16f(hb[e]));
        }
        *(uint2*)&Oh[ob + q * 4] = make_uint2(hb[0] | (hb[1] << 16), hb[2] | (hb[3] << 16));
        *(uint2*)&Ol[ob + q * 4] = make_uint2(lb4[0] | (lb4[1] << 16), lb4[2] | (lb4[3] << 16));
    }
}

// ---------------------------------------------------------------------------
extern "C" void kernel_launch(void* const* d_in, const int* in_sizes, int n_in,
                              void* d_out, int out_size, void* d_ws, size_t ws_size,
                              hipStream_t stream) {
    const float* x   = (const float*)d_in[0];
    const float* Wq  = (const float*)d_in[1];
    const float* bq  = (const float*)d_in[2];
    const float* Wk  = (const float*)d_in[3];
    const float* bk  = (const float*)d_in[4];
    const float* Wv  = (const float*)d_in[5];
    const float* bv  = (const float*)d_in[6];
    const float* Wo  = (const float*)d_in[7];
    const float* bo  = (const float*)d_in[8];
    const float* rel = (const float*)d_in[9];
    float* out = (float*)d_out;

    const size_t NP = (size_t)B_ * H_ * S_ * DK_;   // 2,097,152
    const size_t WP = (size_t)D_ * D_;              //   262,144
    ushort* Xh  = (ushort*)d_ws;
    ushort* Xl  = Xh + NP;
    ushort* Wqh = Xl + NP;
    ushort* Wql = Wqh + WP;
    ushort* Wkh = Wql + WP;
    ushort* Wkl = Wkh + WP;
    ushort* Wvh = Wkl + WP;
    ushort* Wvl = Wvh + WP;
    ushort* Woh = Wvl + WP;
    ushort* Wol = Woh + WP;
    ushort* Qh  = Wol + WP;
    ushort* Ql  = Qh + NP;
    ushort* Kh  = Ql + NP;
    ushort* Kl  = Kh + NP;                    // layout placeholder
    ushort* Vh  = Kl + NP;
    ushort* Rg  = Vh + NP;                    // 589,824 ushorts
    float*  Op1 = (float*)(Rg + 589824);      // NP floats
    float2* Ml0 = (float2*)(Op1 + NP);        // 32768 float2
    float2* Ml1 = Ml0 + 32768;
    float*  Op0 = (float*)d_ws;               // overlays Xh,Xl (dead after proj)

    conv_pl<<<4224, 256, 0, stream>>>(x, Wq, Wk, Wv, Wo, rel,
                                      Xh, Xl, Wqh, Wql, Wkh, Wkl, Wvh, Wvl, Woh, Wol, Rg);

    // Q and K projections fused via grid.z; K scaled by 1/8, K lo-plane skipped
    gemm_mfma<0, 2><<<dim3(8, 64, 2), 256, 0, stream>>>(
        Xh, Xl, Wqh, Wql, Wkh, Wkl, bq, bk, 1.0f, 0.125f,
        nullptr, Qh, Ql, Kh, nullptr);
    // V projection, operand-swapped -> V^T hi plane (B-side = X, hi only)
    gemm_mfma<0, 3><<<dim3(64, 8, 1), 256, 0, stream>>>(
        Wvh, Wvl, Xh, Xl, nullptr, nullptr, bv, nullptr, 1.0f, 1.0f,
        nullptr, Vh, nullptr, nullptr, nullptr);

    // split-K attention: O^T partials (Op0 overlays X planes, now dead)
    attn_mfma<<<dim3(8, 64, 2), 256, 0, stream>>>(
        Qh, Ql, Kh, Vh, Rg, Op0, Op1, Ml0, Ml1);

    // combine + transpose -> O planes (overlay Kh,Kl region, dead after attn)
    attn_combine<<<dim3(8, 64), 256, 0, stream>>>(Op0, Op1, Ml0, Ml1, Kh, Kl);

    // output projection reads O planes (blocked layout), writes fp32
    gemm_mfma<1, 0><<<dim3(8, 64, 1), 256, 0, stream>>>(
        Kh, Kl, Woh, Wol, nullptr, nullptr, bo, nullptr, 1.0f, 1.0f,
        out, nullptr, nullptr, nullptr, nullptr);
}

// Round 13
// 90.244 us; speedup vs baseline: 1.4699x; 1.0160x over previous
//
#include <hip/hip_runtime.h>
#include <math.h>

#define B_  8
#define S_  512
#define D_  512
#define H_  8
#define DK_ 64

typedef __attribute__((ext_vector_type(8))) short short8;
typedef __attribute__((ext_vector_type(4))) float f32x4;

#define MFMA_BF16(a, b, c) __builtin_amdgcn_mfma_f32_16x16x32_bf16(a, b, c, 0, 0, 0)

__device__ __forceinline__ unsigned bf16_rne(float x) {
    unsigned u = __float_as_uint(x);
    return (u + 0x7FFFu + ((u >> 16) & 1u)) >> 16;
}
__device__ __forceinline__ float bf16f(unsigned h) { return __uint_as_float(h << 16); }

// async global->LDS, 16B per lane; LDS dest wave-uniform (base + lane*16)
__device__ __forceinline__ void glds16(const ushort* g, ushort* l) {
    __builtin_amdgcn_global_load_lds(
        (const __attribute__((address_space(1))) unsigned int*)g,
        (__attribute__((address_space(3))) unsigned int*)l,
        16, 0, 0);
}

// ---------------------------------------------------------------------------
// fp32 -> split-bf16 planes for x, the four weights, AND the rel table.
// grid = 2048 (x) + 1024 (W) + 1152 (rel) = 4224 blocks.  (verbatim R12)
// ---------------------------------------------------------------------------
__global__ __launch_bounds__(256)
void conv_pl(const float* __restrict__ x,
             const float* __restrict__ wq, const float* __restrict__ wk,
             const float* __restrict__ wv, const float* __restrict__ wo,
             const float* __restrict__ rel,
             ushort* __restrict__ Xh, ushort* __restrict__ Xl,
             ushort* __restrict__ Wqh, ushort* __restrict__ Wql,
             ushort* __restrict__ Wkh, ushort* __restrict__ Wkl,
             ushort* __restrict__ Wvh, ushort* __restrict__ Wvl,
             ushort* __restrict__ Woh, ushort* __restrict__ Wol,
             ushort* __restrict__ Rg) {
    const int bid = blockIdx.x;
    if (bid >= 3072) {   // rel table -> padded per-head bf16 Rg[8][1152][64]
        const int idx = (bid - 3072) * 256 + threadIdx.x;
        const int d2 = idx & 31;
        const int rr = (idx >> 5) % 1152;
        const int h  = idx / (1152 * 32);
        unsigned v0 = 0, v1 = 0;
        if (rr >= 64 && rr < 64 + 1023) {
            const float* s = &rel[(size_t)(rr - 64) * 512 + h * 64 + d2 * 2];
            v0 = bf16_rne(s[0]); v1 = bf16_rne(s[1]);
        }
        *(uint*)&Rg[((size_t)h * 1152 + rr) * 64 + d2 * 2] = v0 | (v1 << 16);
        return;
    }
    const float* src; ushort* dh; ushort* dl; int i4;
    if (bid < 2048) {
        src = x; dh = Xh; dl = Xl; i4 = bid * 256 + threadIdx.x;
    } else {
        const int r = bid - 2048;
        const int wsel = r >> 8;
        src = (wsel == 0) ? wq : (wsel == 1) ? wk : (wsel == 2) ? wv : wo;
        dh  = (wsel == 0) ? Wqh : (wsel == 1) ? Wkh : (wsel == 2) ? Wvh : Woh;
        dl  = (wsel == 0) ? Wql : (wsel == 1) ? Wkl : (wsel == 2) ? Wvl : Wol;
        i4 = (r & 255) * 256 + threadIdx.x;
    }
    const float4 v = ((const float4*)src)[i4];
    unsigned h[4], l[4];
    const float* vp = &v.x;
    #pragma unroll
    for (int j = 0; j < 4; ++j) { h[j] = bf16_rne(vp[j]); l[j] = bf16_rne(vp[j] - bf16f(h[j])); }
    ((uint2*)dh)[i4] = make_uint2(h[0] | (h[1] << 16), h[2] | (h[3] << 16));
    ((uint2*)dl)[i4] = make_uint2(l[0] | (l[1] << 16), l[2] | (l[3] << 16));
}

// ---------------------------------------------------------------------------
// Split-bf16 MFMA GEMM (verbatim R12): 2-term (Xh.Bh + Xl.Bh), 48 KB LDS,
// 3 blocks/CU, 16 MFMA per K-step, 24 wave-uniform staging segments.
// ---------------------------------------------------------------------------
template<int XB, int OM>
__global__ __launch_bounds__(256, 3)
void gemm_mfma(const ushort* __restrict__ Xhp, const ushort* __restrict__ Xlp,
               const ushort* __restrict__ Yh0, const ushort* __restrict__ Yl0,
               const ushort* __restrict__ Yh1, const ushort* __restrict__ Yl1,
               const float* __restrict__ bias0, const float* __restrict__ bias1,
               float scale0, float scale1,
               float* __restrict__ outF,
               ushort* __restrict__ oh0, ushort* __restrict__ ol0,
               ushort* __restrict__ oh1, ushort* __restrict__ ol1) {
    __shared__ ushort Xs[2][2][64 * 64];   // 32 KB
    __shared__ ushort Ys[2][64 * 64];      // 16 KB (hi plane only)

    const int z = blockIdx.z;
    const ushort* Yhp = z ? Yh1 : Yh0;
    const float*  bias = z ? bias1 : bias0;
    const float   scale = z ? scale1 : scale0;
    ushort* ohp = z ? oh1 : oh0;
    ushort* olp = z ? ol1 : ol0;

    const int tid = threadIdx.x;
    const int w = tid >> 6, lane = tid & 63;
    const int g = lane >> 4, c = lane & 15;
    const int rloc = lane >> 3, cc8 = lane & 7;
    const int cp = cc8 ^ rloc;
    const int r0 = blockIdx.y * 64;
    const int c0 = blockIdx.x * 64;

    const f32x4 fz = {0.f, 0.f, 0.f, 0.f};
    f32x4 acc[2][2] = {{fz, fz}, {fz, fz}};

    auto stage = [&](int kt, int buf) {
        const int k0 = kt * 64;
        #pragma unroll
        for (int j = 0; j < 6; ++j) {
            const int seg = w * 6 + j;          // 0..23, wave-uniform
            const int p = seg >> 3;             // 0:Xh 1:Xl 2:Yh
            const int rgrp = seg & 7;
            const int row = rgrp * 8 + rloc;
            const ushort* gb;
            if (p == 2) {
                gb = Yhp + (size_t)(c0 + row) * 512 + k0 + cp * 8;
            } else {
                const ushort* Xp = p ? Xlp : Xhp;
                if (XB == 0) {
                    gb = Xp + (size_t)(r0 + row) * 512 + k0 + cp * 8;
                } else {
                    const int b = r0 >> 9, s0 = r0 & 511, hh = k0 >> 6;
                    gb = Xp + (((size_t)(b * 8 + hh)) * 512 + s0 + row) * 64 + cp * 8;
                }
            }
            ushort* lb = (p == 2) ? &Ys[buf][0] : &Xs[buf][p][0];
            glds16(gb, lb + rgrp * 512);
        }
    };

    auto compute = [&](int buf) {
        #pragma unroll
        for (int ks = 0; ks < 2; ++ks) {
            short8 axh[2], axl[2], byh[2];
            const int wm = (w >> 1) * 32, wn = (w & 1) * 32;
            #pragma unroll
            for (int t = 0; t < 2; ++t) {
                int row = wm + t * 16 + c;
                int off = row * 64 + (((ks * 4 + g) ^ (row & 7)) * 8);
                axh[t] = *(const short8*)&Xs[buf][0][off];
                axl[t] = *(const short8*)&Xs[buf][1][off];
                row = wn + t * 16 + c;
                off = row * 64 + (((ks * 4 + g) ^ (row & 7)) * 8);
                byh[t] = *(const short8*)&Ys[buf][off];
            }
            #pragma unroll
            for (int tm = 0; tm < 2; ++tm)
                #pragma unroll
                for (int tn = 0; tn < 2; ++tn) {
                    acc[tm][tn] = MFMA_BF16(axh[tm], byh[tn], acc[tm][tn]);
                    acc[tm][tn] = MFMA_BF16(axl[tm], byh[tn], acc[tm][tn]);
                }
        }
    };

    stage(0, 0);
    __syncthreads();
    for (int kt = 0; kt < 8; ++kt) {
        if (kt < 7) stage(kt + 1, (kt + 1) & 1);
        compute(kt & 1);
        __syncthreads();
    }

    const int wm = (w >> 1) * 32, wn = (w & 1) * 32;
    if (OM == 0) {
        #pragma unroll
        for (int tn = 0; tn < 2; ++tn) {
            const int gc = c0 + wn + tn * 16 + c;
            const float bv = bias[gc];
            #pragma unroll
            for (int tm = 0; tm < 2; ++tm)
                #pragma unroll
                for (int i = 0; i < 4; ++i) {
                    const int gr = r0 + wm + tm * 16 + g * 4 + i;
                    outF[(size_t)gr * 512 + gc] = acc[tm][tn][i] + bv;
                }
        }
    } else if (OM == 2) {
        #pragma unroll
        for (int tn = 0; tn < 2; ++tn) {
            const int gc = c0 + wn + tn * 16 + c;
            const int h = gc >> 6, dk = gc & 63;
            const float bv = bias[gc];
            #pragma unroll
            for (int tm = 0; tm < 2; ++tm)
                #pragma unroll
                for (int i = 0; i < 4; ++i) {
                    const int gr = r0 + wm + tm * 16 + g * 4 + i;
                    const int b = gr >> 9, s = gr & 511;
                    const float v = (acc[tm][tn][i] + bv) * scale;
                    const unsigned hb = bf16_rne(v);
                    const size_t a = (((size_t)(b * 8 + h)) * 512 + s) * 64 + dk;
                    ohp[a] = (ushort)hb;
                    if (olp) olp[a] = (ushort)bf16_rne(v - bf16f(hb));
                }
        }
    } else { // OM == 3: V^T, hi plane only
        #pragma unroll
        for (int tm = 0; tm < 2; ++tm)
            #pragma unroll
            for (int i = 0; i < 4; ++i) {
                const int gr = r0 + wm + tm * 16 + g * 4 + i;
                const int h = gr >> 6, dk = gr & 63;
                const float bv = bias[gr];
                #pragma unroll
                for (int tn = 0; tn < 2; ++tn) {
                    const int gc = c0 + wn + tn * 16 + c;
                    const int b = gc >> 9, s = gc & 511;
                    const float v = acc[tm][tn][i] + bv;
                    const size_t a = (((size_t)(b * 8 + h)) * 64 + dk) * 512 + s;
                    ohp[a] = (ushort)bf16_rne(v);
                }
            }
    }
}

// ---------------------------------------------------------------------------
// R13: 8-wave fused split-K attention. Waves 0-3 (half 0) process keys
// 0..255, waves 4-7 (half 1) keys 256..511 — each half runs the R12
// per-tile pipeline verbatim on its own LDS set (w -> wl = w&3). After the
// k-loop, the halves merge IN-BLOCK via LDS (O^T frags in dead Rsm, (m,l)
// in dead Ksm) and write final split-bf16 O planes directly — no global
// partials, no combine kernel. LDS 64 KB -> 2 blocks/CU (16 waves/CU).
// ---------------------------------------------------------------------------
__global__ __launch_bounds__(512, 2)
void attn_mfma8(const ushort* __restrict__ Qhp, const ushort* __restrict__ Qlp,
                const ushort* __restrict__ Khp, const ushort* __restrict__ Vhp,
                const ushort* __restrict__ Rg,
                ushort* __restrict__ Oh, ushort* __restrict__ Ol) {
    __shared__ ushort Ksm[2][64 * 64];    // 16 KB [half], key rows PERMUTED
    __shared__ ushort Vsm[2][64 * 64];    // 16 KB [half] V^T
    __shared__ ushort Rsm[2][128 * 64];   // 32 KB [half] rel band; -> Usm; -> Obuf

    const int tid  = threadIdx.x;
    const int w    = tid >> 6;            // 0..7
    const int half = w >> 2;              // split-K half
    const int wl   = w & 3;               // wave-within-half
    const int tidh = tid & 255;           // thread-within-half
    const int lane = tid & 63;
    const int g    = lane >> 4;
    const int c    = lane & 15;
    const int rloc = lane >> 3, cc8 = lane & 7;
    const int bh   = blockIdx.y;
    const int h    = bh & 7;
    const int qwb  = blockIdx.x * 64;
    const int qw   = qwb + wl * 16;

    ushort* Usm = &Rsm[half][wl * 1376];  // per-(half,wave) 16x86; 4*1376<=8192

    const ushort* KhB = Khp + (size_t)bh * 512 * 64;
    const ushort* VhB = Vhp + (size_t)bh * 64 * 512;
    const ushort* RgH = Rg + (size_t)h * 1152 * 64;

    uint4 rv[4];
    auto issue_rel = [&](int kt) {
        const int rbase = kt * 64 - qwb + 512;   // in [64, 960]
        #pragma unroll
        for (int j = 0; j < 4; ++j) {
            const int cd = j * 256 + tidh, row = cd >> 3, cc = cd & 7;
            rv[j] = *(const uint4*)&RgH[(size_t)(rbase + row) * 64 + cc * 8];
        }
    };

    issue_rel(half * 4);
    short8 qfh[2], qfl[2];
    #pragma unroll
    for (int ks = 0; ks < 2; ++ks) {
        const size_t qi = ((size_t)bh * 512 + qw + c) * 64 + ks * 32 + g * 8;
        qfh[ks] = *(const short8*)&Qhp[qi];
        qfl[ks] = *(const short8*)&Qlp[qi];
    }

    const f32x4 fz = {0.f, 0.f, 0.f, 0.f};
    f32x4 o[4] = {fz, fz, fz, fz};        // O^T: row d = 16dt+4g+i, col q = c
    float m = -INFINITY, l = 0.f;

    for (int t = 0; t < 4; ++t) {
        const int kt = half * 4 + t;
        const int k0 = kt * 64;
        __syncthreads();                  // A: prev tile fully consumed

        // ---- commit prefetched rel band (swizzled ds_write), own half ----
        #pragma unroll
        for (int j = 0; j < 4; ++j) {
            const int cd = j * 256 + tidh, row = cd >> 3, cc = cd & 7;
            *(uint4*)&Rsm[half][row * 64 + ((cc ^ (row & 7)) << 3)] = rv[j];
        }
        // ---- stage Kh (key-permuted) / V^T via glds, own half ----
        if (wl < 2) {
            ushort* lb = &Ksm[half][wl * 32 * 64];
            #pragma unroll
            for (int j = 0; j < 4; ++j) {
                const int row = wl * 32 + j * 8 + rloc;
                const int tcq = row >> 4, cq = row & 15;
                const int key = ((tcq & 1) << 5) + ((cq >> 2) << 3)
                              + ((tcq >> 1) << 2) + (cq & 3);
                glds16(KhB + (size_t)(k0 + key) * 64 + ((cc8 ^ rloc) << 3),
                       lb + j * 512);
            }
        } else {
            const ushort* gb = VhB + k0 + (size_t)(wl - 2) * 32 * 512;
            ushort* lb = &Vsm[half][(wl - 2) * 32 * 64];
            #pragma unroll
            for (int j = 0; j < 4; ++j)
                glds16(gb + (size_t)(j * 8 + rloc) * 512 + ((cc8 ^ rloc) << 3),
                       lb + j * 512);
        }

        // ---- B: raw barrier; drain glds + ds_writes, keep prefetch alive ----
        if (t + 1 < 4) {
            issue_rel(kt + 1);            // 4 loads in flight across the barrier
            asm volatile("s_waitcnt vmcnt(4) lgkmcnt(0)" ::: "memory");
        } else {
            asm volatile("s_waitcnt vmcnt(0) lgkmcnt(0)" ::: "memory");
        }
        __builtin_amdgcn_s_barrier();

        // ---- U tiles: U[q][delta] (1-term) from LDS rel band ----
        f32x4 u[5];
        #pragma unroll
        for (int ut = 0; ut < 5; ++ut) u[ut] = fz;
        #pragma unroll
        for (int ks = 0; ks < 2; ++ks)
            #pragma unroll
            for (int ut = 0; ut < 5; ++ut) {
                const int rl = 48 - 16 * wl + c + ut * 16;
                const short8 rf = *(const short8*)
                    &Rsm[half][rl * 64 + (((ks * 4 + g) ^ (c & 7)) << 3)];
                u[ut] = MFMA_BF16(qfh[ks], rf, u[ut]);
            }

        // ---- S^T tiles: mfma(A=Kh permuted rows, B=Q), 2-term split ----
        f32x4 st[4];
        #pragma unroll
        for (int tc = 0; tc < 4; ++tc) st[tc] = fz;
        #pragma unroll
        for (int ks = 0; ks < 2; ++ks)
            #pragma unroll
            for (int tc = 0; tc < 4; ++tc) {
                const int row = tc * 16 + c;
                const int chv = ((ks * 4 + g) ^ (row & 7)) * 8;
                const short8 kh8 = *(const short8*)&Ksm[half][row * 64 + chv];
                st[tc] = MFMA_BF16(kh8, qfh[ks], st[tc]);
                st[tc] = MFMA_BF16(kh8, qfl[ks], st[tc]);
            }

        __syncthreads();                  // C: all waves done reading Rsm

        // ---- U frag -> Usm (aliases own-half Rsm, own-wave region) ----
        #pragma unroll
        for (int ut = 0; ut < 5; ++ut)
            #pragma unroll
            for (int i = 0; i < 4; ++i)
                Usm[(g * 4 + i) * 86 + c + ut * 16] = (ushort)bf16_rne(u[ut][i]);

        asm volatile("s_waitcnt lgkmcnt(0)" ::: "memory");  // U writes visible

        // ---- bias add (scalar LDS reads, direct delta indexing) ----
        #pragma unroll
        for (int tc = 0; tc < 4; ++tc)
            #pragma unroll
            for (int i = 0; i < 4; ++i) {
                const int key = ((tc & 1) << 5) + 8 * g + ((tc >> 1) << 2) + i;
                st[tc][i] += bf16f(Usm[c * 85 + key + 15]);
            }

        // ---- lane-local online softmax ----
        float tm = fmaxf(fmaxf(st[0][0], st[0][1]), fmaxf(st[0][2], st[0][3]));
        #pragma unroll
        for (int tc = 1; tc < 4; ++tc) {
            const float t2 = fmaxf(fmaxf(st[tc][0], st[tc][1]),
                                   fmaxf(st[tc][2], st[tc][3]));
            tm = fmaxf(tm, t2);
        }
        tm = fmaxf(tm, __shfl_xor(tm, 16));
        tm = fmaxf(tm, __shfl_xor(tm, 32));
        const float mn = fmaxf(m, tm);
        const float corr = __expf(m - mn);
        m = mn;
        l *= corr;
        #pragma unroll
        for (int dt = 0; dt < 4; ++dt) o[dt] *= corr;

        uint pk[4][2];
        #pragma unroll
        for (int tc = 0; tc < 4; ++tc) {
            const float p0 = __expf(st[tc][0] - mn);
            const float p1 = __expf(st[tc][1] - mn);
            const float p2 = __expf(st[tc][2] - mn);
            const float p3 = __expf(st[tc][3] - mn);
            l += (p0 + p1) + (p2 + p3);
            pk[tc][0] = bf16_rne(p0) | (bf16_rne(p1) << 16);
            pk[tc][1] = bf16_rne(p2) | (bf16_rne(p3) << 16);
        }

        // ---- PV: O^T += mfma(A=V^T, B=P^T); B-frag is lane-local ----
        #pragma unroll
        for (int ks = 0; ks < 2; ++ks) {
            union { uint u4[4]; short8 s8; } pb;
            pb.u4[0] = pk[ks][0];
            pb.u4[1] = pk[ks][1];
            pb.u4[2] = pk[ks + 2][0];
            pb.u4[3] = pk[ks + 2][1];
            #pragma unroll
            for (int dt = 0; dt < 4; ++dt) {
                const int row = dt * 16 + c;
                const int chv = ((ks * 4 + g) ^ (row & 7)) * 8;
                const short8 vh8 = *(const short8*)&Vsm[half][row * 64 + chv];
                o[dt] = MFMA_BF16(vh8, pb.s8, o[dt]);
            }
        }
    }

    // ---- reduce l across g-groups (m already g-uniform) ----
    float lt = l;
    lt += __shfl_xor(lt, 16);
    lt += __shfl_xor(lt, 32);

    __syncthreads();                      // all tiles done; Rsm/Ksm dead

    // ---- park O^T frags + (m,l) in LDS ----
    float* Ob = (float*)&Rsm[half][0];    // 64x64 f32 = 16 KB (exact fit)
    const int qcol = wl * 16 + c;
    #pragma unroll
    for (int dt = 0; dt < 4; ++dt)
        #pragma unroll
        for (int i = 0; i < 4; ++i)
            Ob[(dt * 16 + g * 4 + i) * 64 + qcol] = o[dt][i];
    float2* MlB = (float2*)&Ksm[0][0];    // 128 float2 = 1 KB
    if (lane < 16) MlB[half * 64 + qcol] = make_float2(m, lt);
    __syncthreads();

    // ---- merge halves, normalize, write split-bf16 O planes ----
    const int q   = tid >> 3;             // 0..63
    const int dk0 = (tid & 7) * 8;        // 0,8,..,56
    const float2 a = MlB[q], b2 = MlB[64 + q];
    const float mm = fmaxf(a.x, b2.x);
    float w0 = __expf(a.x - mm), w1 = __expf(b2.x - mm);
    const float inv = 1.0f / (a.y * w0 + b2.y * w1);
    w0 *= inv; w1 *= inv;
    const float* O0 = (const float*)&Rsm[0][0];
    const float* O1 = (const float*)&Rsm[1][0];
    unsigned hb[8], lb8[8];
    #pragma unroll
    for (int e = 0; e < 8; ++e) {
        const int d = dk0 + e;
        const float v = O0[d * 64 + q] * w0 + O1[d * 64 + q] * w1;
        hb[e] = bf16_rne(v);
        lb8[e] = bf16_rne(v - bf16f(hb[e]));
    }
    const size_t ob = ((size_t)bh * 512 + qwb + q) * 64 + dk0;
    *(uint4*)&Oh[ob] = make_uint4(hb[0] | (hb[1] << 16), hb[2] | (hb[3] << 16),
                                  hb[4] | (hb[5] << 16), hb[6] | (hb[7] << 16));
    *(uint4*)&Ol[ob] = make_uint4(lb8[0] | (lb8[1] << 16), lb8[2] | (lb8[3] << 16),
                                  lb8[4] | (lb8[5] << 16), lb8[6] | (lb8[7] << 16));
}

// ---------------------------------------------------------------------------
extern "C" void kernel_launch(void* const* d_in, const int* in_sizes, int n_in,
                              void* d_out, int out_size, void* d_ws, size_t ws_size,
                              hipStream_t stream) {
    const float* x   = (const float*)d_in[0];
    const float* Wq  = (const float*)d_in[1];
    const float* bq  = (const float*)d_in[2];
    const float* Wk  = (const float*)d_in[3];
    const float* bk  = (const float*)d_in[4];
    const float* Wv  = (const float*)d_in[5];
    const float* bv  = (const float*)d_in[6];
    const float* Wo  = (const float*)d_in[7];
    const float* bo  = (const float*)d_in[8];
    const float* rel = (const float*)d_in[9];
    float* out = (float*)d_out;

    const size_t NP = (size_t)B_ * H_ * S_ * DK_;   // 2,097,152
    const size_t WP = (size_t)D_ * D_;              //   262,144
    ushort* Xh  = (ushort*)d_ws;
    ushort* Xl  = Xh + NP;
    ushort* Wqh = Xl + NP;
    ushort* Wql = Wqh + WP;
    ushort* Wkh = Wql + WP;
    ushort* Wkl = Wkh + WP;
    ushort* Wvh = Wkl + WP;
    ushort* Wvl = Wvh + WP;
    ushort* Woh = Wvl + WP;
    ushort* Wol = Woh + WP;
    ushort* Qh  = Wol + WP;
    ushort* Ql  = Qh + NP;
    ushort* Kh  = Ql + NP;
    ushort* Kl  = Kh + NP;                    // layout placeholder
    ushort* Vh  = Kl + NP;
    ushort* Rg  = Vh + NP;                    // 589,824 ushorts
    ushort* Oh  = Rg + 589824;                // attn output planes
    ushort* Ol  = Oh + NP;

    conv_pl<<<4224, 256, 0, stream>>>(x, Wq, Wk, Wv, Wo, rel,
                                      Xh, Xl, Wqh, Wql, Wkh, Wkl, Wvh, Wvl, Woh, Wol, Rg);

    // Q and K projections fused via grid.z; K scaled by 1/8, K lo-plane skipped
    gemm_mfma<0, 2><<<dim3(8, 64, 2), 256, 0, stream>>>(
        Xh, Xl, Wqh, Wql, Wkh, Wkl, bq, bk, 1.0f, 0.125f,
        nullptr, Qh, Ql, Kh, nullptr);
    // V projection, operand-swapped -> V^T hi plane
    gemm_mfma<0, 3><<<dim3(64, 8, 1), 256, 0, stream>>>(
        Wvh, Wvl, Xh, Xl, nullptr, nullptr, bv, nullptr, 1.0f, 1.0f,
        nullptr, Vh, nullptr, nullptr, nullptr);

    // fused split-K attention: writes O planes directly (no partials/combine)
    attn_mfma8<<<dim3(8, 64), 512, 0, stream>>>(
        Qh, Ql, Kh, Vh, Rg, Oh, Ol);

    // output projection reads O planes (blocked layout), writes fp32
    gemm_mfma<1, 0><<<dim3(8, 64, 1), 256, 0, stream>>>(
        Oh, Ol, Woh, Wol, nullptr, nullptr, bo, nullptr, 1.0f, 1.0f,
        out, nullptr, nullptr, nullptr, nullptr);
}

// Round 14
// 88.872 us; speedup vs baseline: 1.4926x; 1.0154x over previous
//
#include <hip/hip_runtime.h>
#include <math.h>

#define B_  8
#define S_  512
#define D_  512
#define H_  8
#define DK_ 64

typedef __attribute__((ext_vector_type(8))) short short8;
typedef __attribute__((ext_vector_type(4))) float f32x4;

#define MFMA_BF16(a, b, c) __builtin_amdgcn_mfma_f32_16x16x32_bf16(a, b, c, 0, 0, 0)

__device__ __forceinline__ unsigned bf16_rne(float x) {
    unsigned u = __float_as_uint(x);
    return (u + 0x7FFFu + ((u >> 16) & 1u)) >> 16;
}
__device__ __forceinline__ float bf16f(unsigned h) { return __uint_as_float(h << 16); }

// async global->LDS, 16B per lane; LDS dest wave-uniform (base + lane*16)
__device__ __forceinline__ void glds16(const ushort* g, ushort* l) {
    __builtin_amdgcn_global_load_lds(
        (const __attribute__((address_space(1))) unsigned int*)g,
        (__attribute__((address_space(3))) unsigned int*)l,
        16, 0, 0);
}

// ---------------------------------------------------------------------------
// fp32 -> split-bf16 planes for x, the four weights, AND the rel table.
// ---------------------------------------------------------------------------
__global__ __launch_bounds__(256)
void conv_pl(const float* __restrict__ x,
             const float* __restrict__ wq, const float* __restrict__ wk,
             const float* __restrict__ wv, const float* __restrict__ wo,
             const float* __restrict__ rel,
             ushort* __restrict__ Xh, ushort* __restrict__ Xl,
             ushort* __restrict__ Wqh, ushort* __restrict__ Wql,
             ushort* __restrict__ Wkh, ushort* __restrict__ Wkl,
             ushort* __restrict__ Wvh, ushort* __restrict__ Wvl,
             ushort* __restrict__ Woh, ushort* __restrict__ Wol,
             ushort* __restrict__ Rg) {
    const int bid = blockIdx.x;
    if (bid >= 3072) {
        const int idx = (bid - 3072) * 256 + threadIdx.x;
        const int d2 = idx & 31;
        const int rr = (idx >> 5) % 1152;
        const int h  = idx / (1152 * 32);
        unsigned v0 = 0, v1 = 0;
        if (rr >= 64 && rr < 64 + 1023) {
            const float* s = &rel[(size_t)(rr - 64) * 512 + h * 64 + d2 * 2];
            v0 = bf16_rne(s[0]); v1 = bf16_rne(s[1]);
        }
        *(uint*)&Rg[((size_t)h * 1152 + rr) * 64 + d2 * 2] = v0 | (v1 << 16);
        return;
    }
    const float* src; ushort* dh; ushort* dl; int i4;
    if (bid < 2048) {
        src = x; dh = Xh; dl = Xl; i4 = bid * 256 + threadIdx.x;
    } else {
        const int r = bid - 2048;
        const int wsel = r >> 8;
        src = (wsel == 0) ? wq : (wsel == 1) ? wk : (wsel == 2) ? wv : wo;
        dh  = (wsel == 0) ? Wqh : (wsel == 1) ? Wkh : (wsel == 2) ? Wvh : Woh;
        dl  = (wsel == 0) ? Wql : (wsel == 1) ? Wkl : (wsel == 2) ? Wvl : Wol;
        i4 = (r & 255) * 256 + threadIdx.x;
    }
    const float4 v = ((const float4*)src)[i4];
    unsigned h[4], l[4];
    const float* vp = &v.x;
    #pragma unroll
    for (int j = 0; j < 4; ++j) { h[j] = bf16_rne(vp[j]); l[j] = bf16_rne(vp[j] - bf16f(h[j])); }
    ((uint2*)dh)[i4] = make_uint2(h[0] | (h[1] << 16), h[2] | (h[3] << 16));
    ((uint2*)dl)[i4] = make_uint2(l[0] | (l[1] << 16), l[2] | (l[3] << 16));
}

// ---------------------------------------------------------------------------
// Split-bf16 MFMA GEMM (R14: counted-vmcnt barriers — prefetch glds stay in
// flight across the pre-compute barrier; plain raw barrier after compute).
// ---------------------------------------------------------------------------
template<int XB, int OM>
__global__ __launch_bounds__(256, 3)
void gemm_mfma(const ushort* __restrict__ Xhp, const ushort* __restrict__ Xlp,
               const ushort* __restrict__ Yh0, const ushort* __restrict__ Yl0,
               const ushort* __restrict__ Yh1, const ushort* __restrict__ Yl1,
               const float* __restrict__ bias0, const float* __restrict__ bias1,
               float scale0, float scale1,
               float* __restrict__ outF,
               ushort* __restrict__ oh0, ushort* __restrict__ ol0,
               ushort* __restrict__ oh1, ushort* __restrict__ ol1) {
    __shared__ ushort Xs[2][2][64 * 64];   // 32 KB
    __shared__ ushort Ys[2][64 * 64];      // 16 KB

    const int z = blockIdx.z;
    const ushort* Yhp = z ? Yh1 : Yh0;
    const float*  bias = z ? bias1 : bias0;
    const float   scale = z ? scale1 : scale0;
    ushort* ohp = z ? oh1 : oh0;
    ushort* olp = z ? ol1 : ol0;

    const int tid = threadIdx.x;
    const int w = tid >> 6, lane = tid & 63;
    const int g = lane >> 4, c = lane & 15;
    const int rloc = lane >> 3, cc8 = lane & 7;
    const int cp = cc8 ^ rloc;
    const int r0 = blockIdx.y * 64;
    const int c0 = blockIdx.x * 64;

    const f32x4 fz = {0.f, 0.f, 0.f, 0.f};
    f32x4 acc[2][2] = {{fz, fz}, {fz, fz}};

    auto stage = [&](int kt, int buf) {
        const int k0 = kt * 64;
        #pragma unroll
        for (int j = 0; j < 6; ++j) {
            const int seg = w * 6 + j;
            const int p = seg >> 3;
            const int rgrp = seg & 7;
            const int row = rgrp * 8 + rloc;
            const ushort* gb;
            if (p == 2) {
                gb = Yhp + (size_t)(c0 + row) * 512 + k0 + cp * 8;
            } else {
                const ushort* Xp = p ? Xlp : Xhp;
                if (XB == 0) {
                    gb = Xp + (size_t)(r0 + row) * 512 + k0 + cp * 8;
                } else {
                    const int b = r0 >> 9, s0 = r0 & 511, hh = k0 >> 6;
                    gb = Xp + (((size_t)(b * 8 + hh)) * 512 + s0 + row) * 64 + cp * 8;
                }
            }
            ushort* lb = (p == 2) ? &Ys[buf][0] : &Xs[buf][p][0];
            glds16(gb, lb + rgrp * 512);
        }
    };

    auto compute = [&](int buf) {
        #pragma unroll
        for (int ks = 0; ks < 2; ++ks) {
            short8 axh[2], axl[2], byh[2];
            const int wm = (w >> 1) * 32, wn = (w & 1) * 32;
            #pragma unroll
            for (int t = 0; t < 2; ++t) {
                int row = wm + t * 16 + c;
                int off = row * 64 + (((ks * 4 + g) ^ (row & 7)) * 8);
                axh[t] = *(const short8*)&Xs[buf][0][off];
                axl[t] = *(const short8*)&Xs[buf][1][off];
                row = wn + t * 16 + c;
                off = row * 64 + (((ks * 4 + g) ^ (row & 7)) * 8);
                byh[t] = *(const short8*)&Ys[buf][off];
            }
            #pragma unroll
            for (int tm = 0; tm < 2; ++tm)
                #pragma unroll
                for (int tn = 0; tn < 2; ++tn) {
                    acc[tm][tn] = MFMA_BF16(axh[tm], byh[tn], acc[tm][tn]);
                    acc[tm][tn] = MFMA_BF16(axl[tm], byh[tn], acc[tm][tn]);
                }
        }
    };

    stage(0, 0);
    for (int kt = 0; kt < 8; ++kt) {
        if (kt < 7) {
            stage(kt + 1, (kt + 1) & 1);
            asm volatile("s_waitcnt vmcnt(6)" ::: "memory");  // drain only current buf's glds
        } else {
            asm volatile("s_waitcnt vmcnt(0)" ::: "memory");
        }
        __builtin_amdgcn_s_barrier();
        compute(kt & 1);
        __builtin_amdgcn_s_barrier();     // reads of buf done before overwrite
    }

    const int wm = (w >> 1) * 32, wn = (w & 1) * 32;
    if (OM == 0) {
        #pragma unroll
        for (int tn = 0; tn < 2; ++tn) {
            const int gc = c0 + wn + tn * 16 + c;
            const float bv = bias[gc];
            #pragma unroll
            for (int tm = 0; tm < 2; ++tm)
                #pragma unroll
                for (int i = 0; i < 4; ++i) {
                    const int gr = r0 + wm + tm * 16 + g * 4 + i;
                    outF[(size_t)gr * 512 + gc] = acc[tm][tn][i] + bv;
                }
        }
    } else if (OM == 2) {
        #pragma unroll
        for (int tn = 0; tn < 2; ++tn) {
            const int gc = c0 + wn + tn * 16 + c;
            const int h = gc >> 6, dk = gc & 63;
            const float bv = bias[gc];
            #pragma unroll
            for (int tm = 0; tm < 2; ++tm)
                #pragma unroll
                for (int i = 0; i < 4; ++i) {
                    const int gr = r0 + wm + tm * 16 + g * 4 + i;
                    const int b = gr >> 9, s = gr & 511;
                    const float v = (acc[tm][tn][i] + bv) * scale;
                    const unsigned hb = bf16_rne(v);
                    const size_t a = (((size_t)(b * 8 + h)) * 512 + s) * 64 + dk;
                    ohp[a] = (ushort)hb;
                    if (olp) olp[a] = (ushort)bf16_rne(v - bf16f(hb));
                }
        }
    } else { // OM == 3: V^T, hi plane only
        #pragma unroll
        for (int tm = 0; tm < 2; ++tm)
            #pragma unroll
            for (int i = 0; i < 4; ++i) {
                const int gr = r0 + wm + tm * 16 + g * 4 + i;
                const int h = gr >> 6, dk = gr & 63;
                const float bv = bias[gr];
                #pragma unroll
                for (int tn = 0; tn < 2; ++tn) {
                    const int gc = c0 + wn + tn * 16 + c;
                    const int b = gc >> 9, s = gc & 511;
                    const float v = acc[tm][tn][i] + bv;
                    const size_t a = (((size_t)(b * 8 + h)) * 64 + dk) * 512 + s;
                    ohp[a] = (ushort)bf16_rne(v);
                }
            }
    }
}

// ---------------------------------------------------------------------------
// R14 attention = R13 + (1) setprio around MFMA clusters (T5),
// (2) Usm stride 89 / offset 1 -> bias reads are 4 aligned ds_read_b64,
// (3) rotated merge-epilogue layout (kills the 1M bank conflicts).
// ---------------------------------------------------------------------------
__global__ __launch_bounds__(512, 2)
void attn_mfma8(const ushort* __restrict__ Qhp, const ushort* __restrict__ Qlp,
                const ushort* __restrict__ Khp, const ushort* __restrict__ Vhp,
                const ushort* __restrict__ Rg,
                ushort* __restrict__ Oh, ushort* __restrict__ Ol) {
    __shared__ ushort Ksm[2][64 * 64];    // 16 KB [half], key rows PERMUTED
    __shared__ ushort Vsm[2][64 * 64];    // 16 KB [half] V^T
    __shared__ ushort Rsm[2][128 * 64];   // 32 KB [half] rel band; -> Usm; -> Obuf

    const int tid  = threadIdx.x;
    const int w    = tid >> 6;
    const int half = w >> 2;
    const int wl   = w & 3;
    const int tidh = tid & 255;
    const int lane = tid & 63;
    const int g    = lane >> 4;
    const int c    = lane & 15;
    const int rloc = lane >> 3, cc8 = lane & 7;
    const int bh   = blockIdx.y;
    const int h    = bh & 7;
    const int qwb  = blockIdx.x * 64;
    const int qw   = qwb + wl * 16;

    // Usm: stride 89, base offset 1 -> reader addr 88c+key+16 is 8B-aligned
    ushort* Usm = &Rsm[half][wl * 1424];  // 4*1424 = 5696 <= 8192

    const ushort* KhB = Khp + (size_t)bh * 512 * 64;
    const ushort* VhB = Vhp + (size_t)bh * 64 * 512;
    const ushort* RgH = Rg + (size_t)h * 1152 * 64;

    uint4 rv[4];
    auto issue_rel = [&](int kt) {
        const int rbase = kt * 64 - qwb + 512;
        #pragma unroll
        for (int j = 0; j < 4; ++j) {
            const int cd = j * 256 + tidh, row = cd >> 3, cc = cd & 7;
            rv[j] = *(const uint4*)&RgH[(size_t)(rbase + row) * 64 + cc * 8];
        }
    };

    issue_rel(half * 4);
    short8 qfh[2], qfl[2];
    #pragma unroll
    for (int ks = 0; ks < 2; ++ks) {
        const size_t qi = ((size_t)bh * 512 + qw + c) * 64 + ks * 32 + g * 8;
        qfh[ks] = *(const short8*)&Qhp[qi];
        qfl[ks] = *(const short8*)&Qlp[qi];
    }

    const f32x4 fz = {0.f, 0.f, 0.f, 0.f};
    f32x4 o[4] = {fz, fz, fz, fz};
    float m = -INFINITY, l = 0.f;

    for (int t = 0; t < 4; ++t) {
        const int kt = half * 4 + t;
        const int k0 = kt * 64;
        __syncthreads();                  // A: prev tile fully consumed

        #pragma unroll
        for (int j = 0; j < 4; ++j) {
            const int cd = j * 256 + tidh, row = cd >> 3, cc = cd & 7;
            *(uint4*)&Rsm[half][row * 64 + ((cc ^ (row & 7)) << 3)] = rv[j];
        }
        if (wl < 2) {
            ushort* lb = &Ksm[half][wl * 32 * 64];
            #pragma unroll
            for (int j = 0; j < 4; ++j) {
                const int row = wl * 32 + j * 8 + rloc;
                const int tcq = row >> 4, cq = row & 15;
                const int key = ((tcq & 1) << 5) + ((cq >> 2) << 3)
                              + ((tcq >> 1) << 2) + (cq & 3);
                glds16(KhB + (size_t)(k0 + key) * 64 + ((cc8 ^ rloc) << 3),
                       lb + j * 512);
            }
        } else {
            const ushort* gb = VhB + k0 + (size_t)(wl - 2) * 32 * 512;
            ushort* lb = &Vsm[half][(wl - 2) * 32 * 64];
            #pragma unroll
            for (int j = 0; j < 4; ++j)
                glds16(gb + (size_t)(j * 8 + rloc) * 512 + ((cc8 ^ rloc) << 3),
                       lb + j * 512);
        }

        if (t + 1 < 4) {
            issue_rel(kt + 1);
            asm volatile("s_waitcnt vmcnt(4) lgkmcnt(0)" ::: "memory");
        } else {
            asm volatile("s_waitcnt vmcnt(0) lgkmcnt(0)" ::: "memory");
        }
        __builtin_amdgcn_s_barrier();     // B

        // ---- U tiles (MFMA cluster, boosted prio) ----
        __builtin_amdgcn_s_setprio(1);
        f32x4 u[5];
        #pragma unroll
        for (int ut = 0; ut < 5; ++ut) u[ut] = fz;
        #pragma unroll
        for (int ks = 0; ks < 2; ++ks)
            #pragma unroll
            for (int ut = 0; ut < 5; ++ut) {
                const int rl = 48 - 16 * wl + c + ut * 16;
                const short8 rf = *(const short8*)
                    &Rsm[half][rl * 64 + (((ks * 4 + g) ^ (c & 7)) << 3)];
                u[ut] = MFMA_BF16(qfh[ks], rf, u[ut]);
            }

        // ---- S^T tiles: 2-term split ----
        f32x4 st[4];
        #pragma unroll
        for (int tc = 0; tc < 4; ++tc) st[tc] = fz;
        #pragma unroll
        for (int ks = 0; ks < 2; ++ks)
            #pragma unroll
            for (int tc = 0; tc < 4; ++tc) {
                const int row = tc * 16 + c;
                const int chv = ((ks * 4 + g) ^ (row & 7)) * 8;
                const short8 kh8 = *(const short8*)&Ksm[half][row * 64 + chv];
                st[tc] = MFMA_BF16(kh8, qfh[ks], st[tc]);
                st[tc] = MFMA_BF16(kh8, qfl[ks], st[tc]);
            }
        __builtin_amdgcn_s_setprio(0);

        __syncthreads();                  // C: all waves done reading Rsm

        // ---- U frag -> Usm (stride 89, offset 1) ----
        #pragma unroll
        for (int ut = 0; ut < 5; ++ut)
            #pragma unroll
            for (int i = 0; i < 4; ++i)
                Usm[(g * 4 + i) * 89 + c + ut * 16 + 1] = (ushort)bf16_rne(u[ut][i]);

        asm volatile("s_waitcnt lgkmcnt(0)" ::: "memory");

        // ---- bias add: 4 aligned b64 reads (keys key0..key0+3 contiguous) ----
        #pragma unroll
        for (int tc = 0; tc < 4; ++tc) {
            const int key0 = ((tc & 1) << 5) + 8 * g + ((tc >> 1) << 2);
            const uint2 uv = *(const uint2*)&Usm[88 * c + key0 + 16];
            st[tc][0] += bf16f(uv.x & 0xffffu);
            st[tc][1] += bf16f(uv.x >> 16);
            st[tc][2] += bf16f(uv.y & 0xffffu);
            st[tc][3] += bf16f(uv.y >> 16);
        }

        // ---- lane-local online softmax ----
        float tm = fmaxf(fmaxf(st[0][0], st[0][1]), fmaxf(st[0][2], st[0][3]));
        #pragma unroll
        for (int tc = 1; tc < 4; ++tc) {
            const float t2 = fmaxf(fmaxf(st[tc][0], st[tc][1]),
                                   fmaxf(st[tc][2], st[tc][3]));
            tm = fmaxf(tm, t2);
        }
        tm = fmaxf(tm, __shfl_xor(tm, 16));
        tm = fmaxf(tm, __shfl_xor(tm, 32));
        const float mn = fmaxf(m, tm);
        const float corr = __expf(m - mn);
        m = mn;
        l *= corr;
        #pragma unroll
        for (int dt = 0; dt < 4; ++dt) o[dt] *= corr;

        uint pk[4][2];
        #pragma unroll
        for (int tc = 0; tc < 4; ++tc) {
            const float p0 = __expf(st[tc][0] - mn);
            const float p1 = __expf(st[tc][1] - mn);
            const float p2 = __expf(st[tc][2] - mn);
            const float p3 = __expf(st[tc][3] - mn);
            l += (p0 + p1) + (p2 + p3);
            pk[tc][0] = bf16_rne(p0) | (bf16_rne(p1) << 16);
            pk[tc][1] = bf16_rne(p2) | (bf16_rne(p3) << 16);
        }

        // ---- PV (MFMA cluster, boosted prio) ----
        __builtin_amdgcn_s_setprio(1);
        #pragma unroll
        for (int ks = 0; ks < 2; ++ks) {
            union { uint u4[4]; short8 s8; } pb;
            pb.u4[0] = pk[ks][0];
            pb.u4[1] = pk[ks][1];
            pb.u4[2] = pk[ks + 2][0];
            pb.u4[3] = pk[ks + 2][1];
            #pragma unroll
            for (int dt = 0; dt < 4; ++dt) {
                const int row = dt * 16 + c;
                const int chv = ((ks * 4 + g) ^ (row & 7)) * 8;
                const short8 vh8 = *(const short8*)&Vsm[half][row * 64 + chv];
                o[dt] = MFMA_BF16(vh8, pb.s8, o[dt]);
            }
        }
        __builtin_amdgcn_s_setprio(0);
    }

    // ---- reduce l across g-groups ----
    float lt = l;
    lt += __shfl_xor(lt, 16);
    lt += __shfl_xor(lt, 32);

    __syncthreads();                      // all tiles done; Rsm/Ksm dead

    // ---- park O^T frags (ROTATED layout) + (m,l) in LDS ----
    float* Ob = (float*)&Rsm[half][0];    // 64x64 f32 = 16 KB
    const int qcol = wl * 16 + c;
    #pragma unroll
    for (int dt = 0; dt < 4; ++dt)
        #pragma unroll
        for (int i = 0; i < 4; ++i) {
            const int row = dt * 16 + g * 4 + i;
            Ob[row * 64 + ((qcol + row) & 63)] = o[dt][i];
        }
    float2* MlB = (float2*)&Ksm[0][0];
    if (lane < 16) MlB[half * 64 + qcol] = make_float2(m, lt);
    __syncthreads();

    // ---- merge halves, normalize, write split-bf16 O planes ----
    const int q   = tid >> 3;
    const int dk0 = (tid & 7) * 8;
    const float2 a = MlB[q], b2 = MlB[64 + q];
    const float mm = fmaxf(a.x, b2.x);
    float w0 = __expf(a.x - mm), w1 = __expf(b2.x - mm);
    const float inv = 1.0f / (a.y * w0 + b2.y * w1);
    w0 *= inv; w1 *= inv;
    const float* O0 = (const float*)&Rsm[0][0];
    const float* O1 = (const float*)&Rsm[1][0];
    unsigned hb[8], lb8[8];
    #pragma unroll
    for (int e = 0; e < 8; ++e) {
        const int d = dk0 + e;
        const int colr = (q + d) & 63;
        const float v = O0[d * 64 + colr] * w0 + O1[d * 64 + colr] * w1;
        hb[e] = bf16_rne(v);
        lb8[e] = bf16_rne(v - bf16f(hb[e]));
    }
    const size_t ob = ((size_t)bh * 512 + qwb + q) * 64 + dk0;
    *(uint4*)&Oh[ob] = make_uint4(hb[0] | (hb[1] << 16), hb[2] | (hb[3] << 16),
                                  hb[4] | (hb[5] << 16), hb[6] | (hb[7] << 16));
    *(uint4*)&Ol[ob] = make_uint4(lb8[0] | (lb8[1] << 16), lb8[2] | (lb8[3] << 16),
                                  lb8[4] | (lb8[5] << 16), lb8[6] | (lb8[7] << 16));
}

// ---------------------------------------------------------------------------
extern "C" void kernel_launch(void* const* d_in, const int* in_sizes, int n_in,
                              void* d_out, int out_size, void* d_ws, size_t ws_size,
                              hipStream_t stream) {
    const float* x   = (const float*)d_in[0];
    const float* Wq  = (const float*)d_in[1];
    const float* bq  = (const float*)d_in[2];
    const float* Wk  = (const float*)d_in[3];
    const float* bk  = (const float*)d_in[4];
    const float* Wv  = (const float*)d_in[5];
    const float* bv  = (const float*)d_in[6];
    const float* Wo  = (const float*)d_in[7];
    const float* bo  = (const float*)d_in[8];
    const float* rel = (const float*)d_in[9];
    float* out = (float*)d_out;

    const size_t NP = (size_t)B_ * H_ * S_ * DK_;   // 2,097,152
    const size_t WP = (size_t)D_ * D_;              //   262,144
    ushort* Xh  = (ushort*)d_ws;
    ushort* Xl  = Xh + NP;
    ushort* Wqh = Xl + NP;
    ushort* Wql = Wqh + WP;
    ushort* Wkh = Wql + WP;
    ushort* Wkl = Wkh + WP;
    ushort* Wvh = Wkl + WP;
    ushort* Wvl = Wvh + WP;
    ushort* Woh = Wvl + WP;
    ushort* Wol = Woh + WP;
    ushort* Qh  = Wol + WP;
    ushort* Ql  = Qh + NP;
    ushort* Kh  = Ql + NP;
    ushort* Kl  = Kh + NP;                    // layout placeholder
    ushort* Vh  = Kl + NP;
    ushort* Rg  = Vh + NP;                    // 589,824 ushorts
    ushort* Oh  = Rg + 589824;                // attn output planes
    ushort* Ol  = Oh + NP;

    conv_pl<<<4224, 256, 0, stream>>>(x, Wq, Wk, Wv, Wo, rel,
                                      Xh, Xl, Wqh, Wql, Wkh, Wkl, Wvh, Wvl, Woh, Wol, Rg);

    // Q and K projections fused via grid.z; K scaled by 1/8, K lo-plane skipped
    gemm_mfma<0, 2><<<dim3(8, 64, 2), 256, 0, stream>>>(
        Xh, Xl, Wqh, Wql, Wkh, Wkl, bq, bk, 1.0f, 0.125f,
        nullptr, Qh, Ql, Kh, nullptr);
    // V projection, operand-swapped -> V^T hi plane
    gemm_mfma<0, 3><<<dim3(64, 8, 1), 256, 0, stream>>>(
        Wvh, Wvl, Xh, Xl, nullptr, nullptr, bv, nullptr, 1.0f, 1.0f,
        nullptr, Vh, nullptr, nullptr, nullptr);

    // fused split-K attention: writes O planes directly
    attn_mfma8<<<dim3(8, 64), 512, 0, stream>>>(
        Qh, Ql, Kh, Vh, Rg, Oh, Ol);

    // output projection reads O planes (blocked layout), writes fp32
    gemm_mfma<1, 0><<<dim3(8, 64, 1), 256, 0, stream>>>(
        Oh, Ol, Woh, Wol, nullptr, nullptr, bo, nullptr, 1.0f, 1.0f,
        out, nullptr, nullptr, nullptr, nullptr);
}